// Round 7
// baseline (3251.924 us; speedup 1.0000x reference)
//
#include <hip/hip_runtime.h>

#define B_  512
#define S_  200
#define E_  512
#define A_  256
#define V_  50000
#define K_  51
#define PADIDX 1

typedef short short8_t __attribute__((ext_vector_type(8)));
typedef float float4_t __attribute__((ext_vector_type(4)));
typedef int   int8v    __attribute__((ext_vector_type(8)));
typedef unsigned short u16;
typedef unsigned int   u32;
typedef unsigned char  u8;

// ---------- f32 -> bf16 RNE (internal staging only) ----------
__device__ __forceinline__ u16 f2b(float f) {
    u32 x = __float_as_uint(f);
    return (u16)((x + 0x7fffu + ((x >> 16) & 1u)) >> 16);
}
// ---------- f32 -> fp8 e4m3 (OCP), via HW cvt ----------
__device__ __forceinline__ u8 f2fp8(float f) {
    int p = __builtin_amdgcn_cvt_pk_fp8_f32(f, 0.f, 0, false);
    return (u8)(p & 0xff);
}

// ---------- async global->LDS, 16B per lane ----------
__device__ __forceinline__ void glds16(const u16* g, short* l) {
    __builtin_amdgcn_global_load_lds(
        (const __attribute__((address_space(1))) unsigned int*)g,
        (__attribute__((address_space(3))) unsigned int*)l, 16, 0, 0);
}
__device__ __forceinline__ void glds16b(const u8* g, const u8* l) {
    __builtin_amdgcn_global_load_lds(
        (const __attribute__((address_space(1))) unsigned int*)g,
        (__attribute__((address_space(3))) unsigned int*)l, 16, 0, 0);
}

// ---------- workspace offsets (bytes); total guard 76,628,992 (proven) ----------
#define GP8_OFF   0ull
#define GP8_BYTES 33587200ull          // 131072 rows * 256 fp8 + 32KB slack
#define AP2_OFF   33587200ull          // packed+swizzled conv weights: 102*32768 fp8
#define RT_OFF    36929536ull          // 1/||T_a||   (256 f32)
#define RX_OFF    36930560ull          // (unused now)
#define M_OFF     37340160ull          // m[b,s]      (102400 f32)
#define T16_OFF   37749760ull          // T in bf16 (512KB)
#define WS_NEEDED 76628992ull

// ================= zero gp8 halo rows: b*256+[0,25) and b*256+[225,250) =================
__global__ __launch_bounds__(256) void k_halo(u8* __restrict__ gp8) {
    int b = blockIdx.x, t = threadIdx.x;
    size_t base = (size_t)b << 16;                 // 256 rows * 256 B
    float4 z = {0.f, 0.f, 0.f, 0.f};
#pragma unroll
    for (int rdx = 0; rdx < 4; rdx++) {
        int q = rdx * 256 + t;
        if (q < 400)      *(float4*)(gp8 + base + (size_t)q * 16) = z;                 // rows [0,25)
        else if (q < 800) *(float4*)(gp8 + base + 57600 + (size_t)(q - 400) * 16) = z; // rows [225,250)
    }
}

// ================= T (f32) -> bf16  +  1/||T_a||  (merged) =================
__global__ __launch_bounds__(64) void k_cvtT(const float* __restrict__ Tf, u16* __restrict__ T16,
                                             float* __restrict__ rt) {
    int a = blockIdx.x, l = threadIdx.x;
    const float* src = Tf + (size_t)a * E_ + l * 8;
    float4 d0 = *(const float4*)(src);
    float4 d1 = *(const float4*)(src + 4);
    ushort4 r0, r1;
    r0.x = f2b(d0.x); r0.y = f2b(d0.y); r0.z = f2b(d0.z); r0.w = f2b(d0.w);
    r1.x = f2b(d1.x); r1.y = f2b(d1.y); r1.z = f2b(d1.z); r1.w = f2b(d1.w);
    *(ushort4*)(T16 + (size_t)a * E_ + l * 8)     = r0;
    *(ushort4*)(T16 + (size_t)a * E_ + l * 8 + 4) = r1;
    float s = d0.x*d0.x + d0.y*d0.y + d0.z*d0.z + d0.w*d0.w
            + d1.x*d1.x + d1.y*d1.y + d1.z*d1.z + d1.w*d1.w;
#pragma unroll
    for (int off = 32; off >= 1; off >>= 1) s += __shfl_xor(s, off, 64);
    if (l == 0) rt[a] = (s > 0.f) ? 1.0f / sqrtf(s) : 0.0f;
}

// ========= pack conv_w (f32) -> ap2[kb][a][granule-swizzled 128B] fp8, scaled x512 =========
// COALESCED (proven R6): one block per output row r; linear float4 reads, LDS transpose,
// line-coalesced 16B stores. Bijection: kk = tap*256+i; kb=kk>>7; j=i&15; lg=(i>>4)&7;
// gslot = lg^(r&7); dst = ap2[kb*32768 + r*128 + gslot*16 + j] = fp8(cwf[r][i][tap]*512).
__global__ __launch_bounds__(256) void k_prepack(const float* __restrict__ cwf, u8* __restrict__ ap2) {
    __shared__ __align__(16) u8 L[13184];
    int r = blockIdx.x, t = threadIdx.x;
    int rs = r & 7;
    const float* src = cwf + (size_t)r * (A_ * K_);

    for (int q = 0; q < 13; q++) {
        int e4 = q * 256 + t;
        if (e4 < 3264) {
            float4 v = ((const float4*)src)[e4];
            float vals[4] = {v.x, v.y, v.z, v.w};
            int id0 = e4 * 4;
#pragma unroll
            for (int u = 0; u < 4; u++) {
                int id  = id0 + u;
                int i   = (int)(((unsigned long long)id * 84215046ull) >> 32);  // exact id/51
                int tap = id - i * 51;
                int kb  = tap * 2 + (i >> 7);
                int j   = i & 15;
                int lg  = (i >> 4) & 7;
                int off7 = ((lg ^ rs) << 4) | j;
                L[kb * 128 + (off7 ^ ((kb & 7) << 4))] = f2fp8(vals[u] * 512.0f);
            }
        }
    }
    __syncthreads();
#pragma unroll
    for (int q = 0; q < 4; q++) {
        int o16 = q * 256 + t;
        if (o16 < 816) {
            int byteo = o16 * 16;
            int kb = byteo >> 7;
            int p  = byteo & 127;
            int4 d = *(const int4*)(L + (byteo & ~127) + (p ^ ((kb & 7) << 4)));
            *(int4*)(ap2 + (size_t)kb * 32768 + (size_t)r * 128 + p) = d;
        }
    }
}

// ================= g = cosine(T, emb[x]) -> gp8[(b*256+25+s)*256 + a] fp8 (x32) =================
// rx (1/||xx_c||) computed IN-KERNEL (R5-proven).
__global__ __launch_bounds__(256) void k_ggemm(const int* __restrict__ x, const float* __restrict__ embf,
                                               const u16* __restrict__ T16, const float* __restrict__ rt,
                                               u8* __restrict__ gp8) {
    __shared__ __align__(16) short Xs[64 * 32];
    __shared__ __align__(16) short Ts[256 * 32];
    int t = threadIdx.x, l = t & 63, w = t >> 6;
    int c0 = blockIdx.x * 64;
    int crow  = t >> 2;
    int xslog = (t & 3) ^ ((crow >> 1) & 3);
    size_t xbase = (size_t)x[c0 + crow] * E_;

    float4_t acc[4][4];
#pragma unroll
    for (int mf = 0; mf < 4; mf++)
#pragma unroll
        for (int nf = 0; nf < 4; nf++) acc[mf][nf] = (float4_t){0.f, 0.f, 0.f, 0.f};

    float ssq = 0.f;                                 // partial ||xx_row||^2 (8 elems/iter)

    for (int ec = 0; ec < 16; ec++) {
        int e0 = ec * 32;
        {
            const float* src = embf + xbase + e0 + xslog * 8;
            float4 f0 = *(const float4*)(src);
            float4 f1 = *(const float4*)(src + 4);
            ssq += f0.x*f0.x + f0.y*f0.y + f0.z*f0.z + f0.w*f0.w
                 + f1.x*f1.x + f1.y*f1.y + f1.z*f1.z + f1.w*f1.w;
            short8_t pk;
            pk[0] = (short)f2b(f0.x); pk[1] = (short)f2b(f0.y);
            pk[2] = (short)f2b(f0.z); pk[3] = (short)f2b(f0.w);
            pk[4] = (short)f2b(f1.x); pk[5] = (short)f2b(f1.y);
            pk[6] = (short)f2b(f1.z); pk[7] = (short)f2b(f1.w);
            *(short8_t*)(Xs + t * 8) = pk;
        }
#pragma unroll
        for (int p = 0; p < 4; p++) {
            int idx  = p * 256 + t;
            int arow = idx >> 2;
            int slog = (idx & 3) ^ ((arow >> 1) & 3);
            glds16(T16 + (size_t)arow * E_ + e0 + slog * 8, Ts + (p * 256 + w * 64) * 8);
        }
        __syncthreads();
        int l15 = l & 15, q = l >> 4;
        short8_t af[4], bf[4];
#pragma unroll
        for (int mf = 0; mf < 4; mf++) {
            int row = mf * 16 + l15;
            int kph = q ^ ((row >> 1) & 3);
            af[mf] = *(const short8_t*)(Xs + row * 32 + kph * 8);
        }
#pragma unroll
        for (int nf = 0; nf < 4; nf++) {
            int row = w * 64 + nf * 16 + l15;
            int kph = q ^ ((row >> 1) & 3);
            bf[nf] = *(const short8_t*)(Ts + row * 32 + kph * 8);
        }
#pragma unroll
        for (int mf = 0; mf < 4; mf++)
#pragma unroll
            for (int nf = 0; nf < 4; nf++)
                acc[mf][nf] = __builtin_amdgcn_mfma_f32_16x16x32_bf16(af[mf], bf[nf], acc[mf][nf], 0, 0, 0);
        __syncthreads();
    }

    // reduce 4 ssq partials per row through dead Xs
    float* rxs = (float*)Xs;
    rxs[t] = ssq;                        // t = crow*4 + (t&3)
    __syncthreads();

    int l15 = l & 15, q = l >> 4;
    float rta[4];
#pragma unroll
    for (int nf = 0; nf < 4; nf++) rta[nf] = rt[w * 64 + nf * 16 + l15];
#pragma unroll
    for (int mf = 0; mf < 4; mf++) {
#pragma unroll
        for (int r = 0; r < 4; r++) {
            int cl = mf * 16 + q * 4 + r;
            int c = c0 + cl;
            float ss = rxs[cl * 4] + rxs[cl * 4 + 1] + rxs[cl * 4 + 2] + rxs[cl * 4 + 3];
            float rxc = ((ss > 0.f) ? 1.0f / sqrtf(ss) : 0.0f) * 32.0f;  // fp8 pre-scale
            int b = (int)(((unsigned long long)c * 167773ull) >> 25);    // exact c/200
            int s = c - b * 200;
            size_t rowoff = (size_t)(b * 256 + 25 + s) * 256;
#pragma unroll
            for (int nf = 0; nf < 4; nf++) {
                int a = w * 64 + nf * 16 + l15;
                gp8[rowoff + a] = f2fp8(acc[mf][nf][r] * rta[nf] * rxc);
            }
        }
    }
}

// ================= conv1d(A->A,k=51)+bias+relu+max_a -> m[col], packed N =================
// 8-WAVE version of the R3-proven loop: 512 threads = (4 row-quarters) x (2 col-tiles).
// A-tile (32KB, kb-dependent only) staged ONCE per chunk for BOTH col-tiles:
// per-tile LDS writes 40KB -> 24KB; per-thread glds 10 -> 6; 24 waves/CU (LDS 48KB x3).
// Reads, MFMA shape, swizzles, acc (4x4, 64 VGPR) identical to R3. Grid 800.
__global__ __launch_bounds__(512, 6) void k_conv(const u8* __restrict__ gp8, const u8* __restrict__ ap2,
                                                 const float* __restrict__ cbf, float* __restrict__ mOut) {
    __shared__ __align__(16) u8 smem[49152];     // As 32KB + Bs 16KB (2 tiles)
    u8* As = smem;
    u8* Bs = smem + 32768;
    float* wred = (float*)smem;                  // aliases As AFTER K-loop's final barrier (2KB)
    int t = threadIdx.x, l = t & 63, w = t >> 6;
    int wq = w & 3, ct = w >> 2;
    int c0 = blockIdx.x * 128;

    // B-staging bases: round p stages cols lc = p*64 + (t>>3) (tile p), granule t&7
    size_t srcb[2];
#pragma unroll
    for (int p = 0; p < 2; p++) {
        int lc = p * 64 + (t >> 3);
        int c = c0 + lc;
        int b = (int)(((unsigned long long)c * 167773ull) >> 25);   // exact c/200
        int s = c - b * 200;
        int gsw = (t & 7) ^ ((t >> 3) & 7);
        srcb[p] = (size_t)(b * 256 + s) * 256 + gsw * 16;
    }

    float4_t acc[4][4];
#pragma unroll
    for (int mf = 0; mf < 4; mf++)
#pragma unroll
        for (int nf = 0; nf < 4; nf++) acc[mf][nf] = (float4_t){0.f, 0.f, 0.f, 0.f};

    int l15 = l & 15, kq = l >> 4;

    for (int kb = 0; kb < 102; kb++) {
        // A: 4 linear rounds, 512 threads (ap2 pre-swizzled) — staged once for both tiles
#pragma unroll
        for (int p = 0; p < 4; p++)
            glds16b(ap2 + ((size_t)kb << 15) + (p << 13) + (t << 4), As + (p << 13) + (w << 10));
        // B: 2 rounds (one per tile); chunk byte offset within row = kb*128
        glds16b(gp8 + srcb[0] + ((size_t)kb << 7), Bs + (w << 10));
        glds16b(gp8 + srcb[1] + ((size_t)kb << 7), Bs + 8192 + (w << 10));
        __syncthreads();

        int8v af[4], bfr[4];
#pragma unroll
        for (int mf = 0; mf < 4; mf++) {
            int row = (wq << 6) + (mf << 4) + l15;
            int sw = row & 7;
            const u8* base = As + (row << 7);
            int4 lo = *(const int4*)(base + ((((kq << 1)    ) ^ sw) << 4));
            int4 hi = *(const int4*)(base + ((((kq << 1) | 1) ^ sw) << 4));
            int8v v; v[0]=lo.x; v[1]=lo.y; v[2]=lo.z; v[3]=lo.w; v[4]=hi.x; v[5]=hi.y; v[6]=hi.z; v[7]=hi.w;
            af[mf] = v;
        }
#pragma unroll
        for (int nf = 0; nf < 4; nf++) {
            int row = (nf << 4) + l15;
            int sw = row & 7;
            const u8* base = Bs + (ct << 13) + (row << 7);
            int4 lo = *(const int4*)(base + ((((kq << 1)    ) ^ sw) << 4));
            int4 hi = *(const int4*)(base + ((((kq << 1) | 1) ^ sw) << 4));
            int8v v; v[0]=lo.x; v[1]=lo.y; v[2]=lo.z; v[3]=lo.w; v[4]=hi.x; v[5]=hi.y; v[6]=hi.z; v[7]=hi.w;
            bfr[nf] = v;
        }
#pragma unroll
        for (int mf = 0; mf < 4; mf++)
#pragma unroll
            for (int nf = 0; nf < 4; nf++)
                acc[mf][nf] = __builtin_amdgcn_mfma_scale_f32_16x16x128_f8f6f4(
                    af[mf], bfr[nf], acc[mf][nf], 0, 0, 0, 0x7F7F7F7F, 0, 0x7F7F7F7F);
        __syncthreads();
    }

    // epilogue: undo 2^14 quant scale, +bias, relu (0-init), max over a
    const float SC = 6.103515625e-05f;   // 2^-14
    float vmax[4] = {0.f, 0.f, 0.f, 0.f};
#pragma unroll
    for (int mf = 0; mf < 4; mf++) {
#pragma unroll
        for (int r = 0; r < 4; r++) {
            float bias = cbf[wq * 64 + mf * 16 + kq * 4 + r];
#pragma unroll
            for (int nf = 0; nf < 4; nf++)
                vmax[nf] = fmaxf(vmax[nf], acc[mf][nf][r] * SC + bias);
        }
    }
#pragma unroll
    for (int nf = 0; nf < 4; nf++) {
        vmax[nf] = fmaxf(vmax[nf], __shfl_xor(vmax[nf], 16, 64));
        vmax[nf] = fmaxf(vmax[nf], __shfl_xor(vmax[nf], 32, 64));
    }
    if (l < 16) {
#pragma unroll
        for (int nf = 0; nf < 4; nf++) wred[ct * 256 + wq * 64 + nf * 16 + l] = vmax[nf];
    }
    __syncthreads();
    if (t < 128) {
        int ct2 = t >> 6, col = t & 63;
        float mm = fmaxf(fmaxf(wred[ct2 * 256 + col],       wred[ct2 * 256 + 64 + col]),
                         fmaxf(wred[ct2 * 256 + 128 + col], wred[ct2 * 256 + 192 + col]));
        mOut[c0 + t] = mm;     // packed: col == b*200+s
    }
}

// ================= FUSED tail: masked softmax -> z_s -> logits -> p_t -> r_s =================
__global__ __launch_bounds__(512) void k_tail(const int* __restrict__ x, const float* __restrict__ embf,
                                              const float* __restrict__ Tf, const float* __restrict__ Wwf,
                                              const float* __restrict__ Wbf, const float* __restrict__ mB,
                                              float* __restrict__ o_pt, float* __restrict__ o_zs,
                                              float* __restrict__ o_rs, float* __restrict__ o_ai,
                                              float* __restrict__ o_ptl) {
    __shared__ float aL[200];
    __shared__ int   tokL[200];
    __shared__ __align__(16) float zL[512];
    __shared__ float pL[256];
    __shared__ float lgt[256];
    __shared__ float red[512];
    __shared__ __align__(16) float part[4][512];
    int b = blockIdx.x, t = threadIdx.x;

    float v = 0.f;
    if (t < 200) {
        int tok = x[b * 200 + t];
        tokL[t] = tok;
        v = (tok == PADIDX) ? -1e13f : mB[b * 200 + t];
        red[t] = v;
    }
    __syncthreads();
    if (t < 64) {
        float m = -3.4e38f;
        for (int i = t; i < 200; i += 64) m = fmaxf(m, red[i]);
#pragma unroll
        for (int off = 32; off >= 1; off >>= 1) m = fmaxf(m, __shfl_xor(m, off, 64));
        if (t == 0) red[200] = m;
    }
    __syncthreads();
    float mx = red[200];
    float e = 0.f;
    if (t < 200) { e = expf(v - mx); red[t] = e; }
    __syncthreads();
    if (t < 64) {
        float s = 0.f;
        for (int i = t; i < 200; i += 64) s += red[i];
#pragma unroll
        for (int off = 32; off >= 1; off >>= 1) s += __shfl_xor(s, off, 64);
        if (t == 0) red[201] = s;
    }
    __syncthreads();
    float ainv = 1.0f / red[201];
    if (t < 200) {
        float a = e * ainv;
        aL[t] = a;
        o_ai[b * 200 + t] = a;
    }
    __syncthreads();

    // z_s: 4 lane-groups x 128 lanes, float4 rows, strided s
    {
        int g = t >> 7, l128 = t & 127;
        float4 zp = {0.f, 0.f, 0.f, 0.f};
        for (int s = g; s < 200; s += 4) {
            float as = aL[s];
            float4 rv = ((const float4*)(embf + (size_t)tokL[s] * E_))[l128];
            zp.x += as * rv.x; zp.y += as * rv.y; zp.z += as * rv.z; zp.w += as * rv.w;
        }
        *(float4*)(&part[g][l128 * 4]) = zp;
    }
    __syncthreads();
    {
        float z = part[0][t] + part[1][t] + part[2][t] + part[3][t];
        zL[t] = z;
        o_zs[(size_t)b * 512 + t] = z;
    }
    __syncthreads();

    // logits: (a = t&255, half h = t>>8), each half sums 256 e-dims
    {
        int a = t & 255, h = t >> 8;
        float acc = (h == 0) ? Wbf[a] : 0.f;
        const float4* wr = (const float4*)(Wwf + (size_t)a * E_ + h * 256);
        const float4* zz = (const float4*)(zL + h * 256);
        for (int i = 0; i < 64; i++) {
            float4 w4 = wr[i]; float4 z4 = zz[i];
            acc += w4.x*z4.x + w4.y*z4.y + w4.z*z4.z + w4.w*z4.w;
        }
        red[t] = acc;
    }
    __syncthreads();
    if (t < 256) {
        float lg = red[t] + red[t + 256];
        lgt[t] = lg;
        o_ptl[(size_t)b * 256 + t] = lg;
    }
    __syncthreads();
    if (t < 64) {
        float m = fmaxf(fmaxf(lgt[t], lgt[t + 64]), fmaxf(lgt[t + 128], lgt[t + 192]));
#pragma unroll
        for (int off = 32; off >= 1; off >>= 1) m = fmaxf(m, __shfl_xor(m, off, 64));
        if (t == 0) red[0] = m;
    }
    __syncthreads();
    float lmx = red[0];
    float pe = 0.f;
    if (t < 256) { pe = expf(lgt[t] - lmx); red[256 + t] = pe; }
    __syncthreads();
    if (t < 64) {
        float s = red[256 + t] + red[256 + t + 64] + red[256 + t + 128] + red[256 + t + 192];
#pragma unroll
        for (int off = 32; off >= 1; off >>= 1) s += __shfl_xor(s, off, 64);
        if (t == 0) red[1] = s;
    }
    __syncthreads();
    float pinv = 1.0f / red[1];
    if (t < 256) {
        float p = pe * pinv;
        pL[t] = p;
        o_pt[(size_t)b * 256 + t] = p;
    }
    __syncthreads();

    // r_s: 4 lane-groups x 128 lanes over a-quarters, float4 rows
    {
        int g = t >> 7, l128 = t & 127;
        float4 rp = {0.f, 0.f, 0.f, 0.f};
        for (int a = g * 64; a < g * 64 + 64; a++) {
            float p = pL[a];
            float4 tv = ((const float4*)(Tf + (size_t)a * E_))[l128];
            rp.x += p * tv.x; rp.y += p * tv.y; rp.z += p * tv.z; rp.w += p * tv.w;
        }
        *(float4*)(&part[g][l128 * 4]) = rp;
    }
    __syncthreads();
    o_rs[(size_t)b * 512 + t] = part[0][t] + part[1][t] + part[2][t] + part[3][t];
}

extern "C" void kernel_launch(void* const* d_in, const int* in_sizes, int n_in,
                              void* d_out, int out_size, void* d_ws, size_t ws_size,
                              hipStream_t stream) {
    if (ws_size < WS_NEEDED) return;
    const int*   x    = (const int*)d_in[0];
    const float* embf = (const float*)d_in[1];
    const float* Tf   = (const float*)d_in[2];
    const float* Wwf  = (const float*)d_in[3];
    const float* Wbf  = (const float*)d_in[4];
    const float* cwf  = (const float*)d_in[5];
    const float* cbf  = (const float*)d_in[6];

    char* ws = (char*)d_ws;
    u8*    gp8 = (u8*)(ws + GP8_OFF);
    u8*    ap2 = (u8*)(ws + AP2_OFF);
    u16*   T16 = (u16*)(ws + T16_OFF);
    float* rt  = (float*)(ws + RT_OFF);
    float* mB  = (float*)(ws + M_OFF);

    float* out   = (float*)d_out;
    float* o_pt  = out;                 // [B,A]
    float* o_zs  = out + 131072;        // [B,E]
    float* o_rs  = out + 393216;        // [B,E]
    float* o_ai  = out + 655360;        // [B,S]
    float* o_ptl = out + 757760;        // [B,A]

    k_halo   <<<512,   256, 0, stream>>>(gp8);
    k_cvtT   <<<256,   64,  0, stream>>>(Tf, T16, rt);
    k_prepack<<<256,   256, 0, stream>>>(cwf, ap2);
    k_ggemm  <<<1600,  256, 0, stream>>>(x, embf, T16, rt, gp8);
    k_conv   <<<800,   512, 0, stream>>>(gp8, ap2, cbf, mB);
    k_tail   <<<512,   512, 0, stream>>>(x, embf, Tf, Wwf, Wbf, mB, o_pt, o_zs, o_rs, o_ai, o_ptl);
}

// Round 8
// 623.007 us; speedup vs baseline: 5.2197x; 5.2197x over previous
//
#include <hip/hip_runtime.h>

#define B_  512
#define S_  200
#define E_  512
#define A_  256
#define V_  50000
#define K_  51
#define PADIDX 1

typedef short short8_t __attribute__((ext_vector_type(8)));
typedef float float4_t __attribute__((ext_vector_type(4)));
typedef int   int8v    __attribute__((ext_vector_type(8)));
typedef unsigned short u16;
typedef unsigned int   u32;
typedef unsigned char  u8;

// ---------- f32 -> bf16 RNE (internal staging only) ----------
__device__ __forceinline__ u16 f2b(float f) {
    u32 x = __float_as_uint(f);
    return (u16)((x + 0x7fffu + ((x >> 16) & 1u)) >> 16);
}
// ---------- f32 -> fp8 e4m3 (OCP), via HW cvt ----------
__device__ __forceinline__ u8 f2fp8(float f) {
    int p = __builtin_amdgcn_cvt_pk_fp8_f32(f, 0.f, 0, false);
    return (u8)(p & 0xff);
}

// ---------- async global->LDS, 16B per lane ----------
__device__ __forceinline__ void glds16(const u16* g, short* l) {
    __builtin_amdgcn_global_load_lds(
        (const __attribute__((address_space(1))) unsigned int*)g,
        (__attribute__((address_space(3))) unsigned int*)l, 16, 0, 0);
}
__device__ __forceinline__ void glds16b(const u8* g, const u8* l) {
    __builtin_amdgcn_global_load_lds(
        (const __attribute__((address_space(1))) unsigned int*)g,
        (__attribute__((address_space(3))) unsigned int*)l, 16, 0, 0);
}

// ---------- workspace offsets (bytes); total guard 76,628,992 (proven) ----------
#define GP8_OFF   0ull
#define GP8_BYTES 33587200ull          // 131072 rows * 256 fp8 + 32KB slack
#define AP2_OFF   33587200ull          // packed+swizzled conv weights: 102*32768 fp8
#define RT_OFF    36929536ull          // 1/||T_a||   (256 f32)
#define RX_OFF    36930560ull          // (unused now)
#define M_OFF     37340160ull          // m[b,s]      (102400 f32)
#define T16_OFF   37749760ull          // T in bf16 (512KB)
#define WS_NEEDED 76628992ull

// ================= zero gp8 halo rows: b*256+[0,25) and b*256+[225,250) =================
__global__ __launch_bounds__(256) void k_halo(u8* __restrict__ gp8) {
    int b = blockIdx.x, t = threadIdx.x;
    size_t base = (size_t)b << 16;                 // 256 rows * 256 B
    float4 z = {0.f, 0.f, 0.f, 0.f};
#pragma unroll
    for (int rdx = 0; rdx < 4; rdx++) {
        int q = rdx * 256 + t;
        if (q < 400)      *(float4*)(gp8 + base + (size_t)q * 16) = z;                 // rows [0,25)
        else if (q < 800) *(float4*)(gp8 + base + 57600 + (size_t)(q - 400) * 16) = z; // rows [225,250)
    }
}

// ================= T (f32) -> bf16  +  1/||T_a||  (merged) =================
__global__ __launch_bounds__(64) void k_cvtT(const float* __restrict__ Tf, u16* __restrict__ T16,
                                             float* __restrict__ rt) {
    int a = blockIdx.x, l = threadIdx.x;
    const float* src = Tf + (size_t)a * E_ + l * 8;
    float4 d0 = *(const float4*)(src);
    float4 d1 = *(const float4*)(src + 4);
    ushort4 r0, r1;
    r0.x = f2b(d0.x); r0.y = f2b(d0.y); r0.z = f2b(d0.z); r0.w = f2b(d0.w);
    r1.x = f2b(d1.x); r1.y = f2b(d1.y); r1.z = f2b(d1.z); r1.w = f2b(d1.w);
    *(ushort4*)(T16 + (size_t)a * E_ + l * 8)     = r0;
    *(ushort4*)(T16 + (size_t)a * E_ + l * 8 + 4) = r1;
    float s = d0.x*d0.x + d0.y*d0.y + d0.z*d0.z + d0.w*d0.w
            + d1.x*d1.x + d1.y*d1.y + d1.z*d1.z + d1.w*d1.w;
#pragma unroll
    for (int off = 32; off >= 1; off >>= 1) s += __shfl_xor(s, off, 64);
    if (l == 0) rt[a] = (s > 0.f) ? 1.0f / sqrtf(s) : 0.0f;
}

// ========= pack conv_w (f32) -> ap2[kb][a][granule-swizzled 128B] fp8, scaled x512 =========
// COALESCED (proven R6): one block per output row r; linear float4 reads, LDS transpose,
// line-coalesced 16B stores. Bijection: kk = tap*256+i; kb=kk>>7; j=i&15; lg=(i>>4)&7;
// gslot = lg^(r&7); dst = ap2[kb*32768 + r*128 + gslot*16 + j] = fp8(cwf[r][i][tap]*512).
__global__ __launch_bounds__(256) void k_prepack(const float* __restrict__ cwf, u8* __restrict__ ap2) {
    __shared__ __align__(16) u8 L[13184];
    int r = blockIdx.x, t = threadIdx.x;
    int rs = r & 7;
    const float* src = cwf + (size_t)r * (A_ * K_);

    for (int q = 0; q < 13; q++) {
        int e4 = q * 256 + t;
        if (e4 < 3264) {
            float4 v = ((const float4*)src)[e4];
            float vals[4] = {v.x, v.y, v.z, v.w};
            int id0 = e4 * 4;
#pragma unroll
            for (int u = 0; u < 4; u++) {
                int id  = id0 + u;
                int i   = (int)(((unsigned long long)id * 84215046ull) >> 32);  // exact id/51
                int tap = id - i * 51;
                int kb  = tap * 2 + (i >> 7);
                int j   = i & 15;
                int lg  = (i >> 4) & 7;
                int off7 = ((lg ^ rs) << 4) | j;
                L[kb * 128 + (off7 ^ ((kb & 7) << 4))] = f2fp8(vals[u] * 512.0f);
            }
        }
    }
    __syncthreads();
#pragma unroll
    for (int q = 0; q < 4; q++) {
        int o16 = q * 256 + t;
        if (o16 < 816) {
            int byteo = o16 * 16;
            int kb = byteo >> 7;
            int p  = byteo & 127;
            int4 d = *(const int4*)(L + (byteo & ~127) + (p ^ ((kb & 7) << 4)));
            *(int4*)(ap2 + (size_t)kb * 32768 + (size_t)r * 128 + p) = d;
        }
    }
}

// ================= g = cosine(T, emb[x]) -> gp8[(b*256+25+s)*256 + a] fp8 (x32) =================
// rx (1/||xx_c||) computed IN-KERNEL (R5-proven).
__global__ __launch_bounds__(256) void k_ggemm(const int* __restrict__ x, const float* __restrict__ embf,
                                               const u16* __restrict__ T16, const float* __restrict__ rt,
                                               u8* __restrict__ gp8) {
    __shared__ __align__(16) short Xs[64 * 32];
    __shared__ __align__(16) short Ts[256 * 32];
    int t = threadIdx.x, l = t & 63, w = t >> 6;
    int c0 = blockIdx.x * 64;
    int crow  = t >> 2;
    int xslog = (t & 3) ^ ((crow >> 1) & 3);
    size_t xbase = (size_t)x[c0 + crow] * E_;

    float4_t acc[4][4];
#pragma unroll
    for (int mf = 0; mf < 4; mf++)
#pragma unroll
        for (int nf = 0; nf < 4; nf++) acc[mf][nf] = (float4_t){0.f, 0.f, 0.f, 0.f};

    float ssq = 0.f;                                 // partial ||xx_row||^2 (8 elems/iter)

    for (int ec = 0; ec < 16; ec++) {
        int e0 = ec * 32;
        {
            const float* src = embf + xbase + e0 + xslog * 8;
            float4 f0 = *(const float4*)(src);
            float4 f1 = *(const float4*)(src + 4);
            ssq += f0.x*f0.x + f0.y*f0.y + f0.z*f0.z + f0.w*f0.w
                 + f1.x*f1.x + f1.y*f1.y + f1.z*f1.z + f1.w*f1.w;
            short8_t pk;
            pk[0] = (short)f2b(f0.x); pk[1] = (short)f2b(f0.y);
            pk[2] = (short)f2b(f0.z); pk[3] = (short)f2b(f0.w);
            pk[4] = (short)f2b(f1.x); pk[5] = (short)f2b(f1.y);
            pk[6] = (short)f2b(f1.z); pk[7] = (short)f2b(f1.w);
            *(short8_t*)(Xs + t * 8) = pk;
        }
#pragma unroll
        for (int p = 0; p < 4; p++) {
            int idx  = p * 256 + t;
            int arow = idx >> 2;
            int slog = (idx & 3) ^ ((arow >> 1) & 3);
            glds16(T16 + (size_t)arow * E_ + e0 + slog * 8, Ts + (p * 256 + w * 64) * 8);
        }
        __syncthreads();
        int l15 = l & 15, q = l >> 4;
        short8_t af[4], bf[4];
#pragma unroll
        for (int mf = 0; mf < 4; mf++) {
            int row = mf * 16 + l15;
            int kph = q ^ ((row >> 1) & 3);
            af[mf] = *(const short8_t*)(Xs + row * 32 + kph * 8);
        }
#pragma unroll
        for (int nf = 0; nf < 4; nf++) {
            int row = w * 64 + nf * 16 + l15;
            int kph = q ^ ((row >> 1) & 3);
            bf[nf] = *(const short8_t*)(Ts + row * 32 + kph * 8);
        }
#pragma unroll
        for (int mf = 0; mf < 4; mf++)
#pragma unroll
            for (int nf = 0; nf < 4; nf++)
                acc[mf][nf] = __builtin_amdgcn_mfma_f32_16x16x32_bf16(af[mf], bf[nf], acc[mf][nf], 0, 0, 0);
        __syncthreads();
    }

    // reduce 4 ssq partials per row through dead Xs
    float* rxs = (float*)Xs;
    rxs[t] = ssq;                        // t = crow*4 + (t&3)
    __syncthreads();

    int l15 = l & 15, q = l >> 4;
    float rta[4];
#pragma unroll
    for (int nf = 0; nf < 4; nf++) rta[nf] = rt[w * 64 + nf * 16 + l15];
#pragma unroll
    for (int mf = 0; mf < 4; mf++) {
#pragma unroll
        for (int r = 0; r < 4; r++) {
            int cl = mf * 16 + q * 4 + r;
            int c = c0 + cl;
            float ss = rxs[cl * 4] + rxs[cl * 4 + 1] + rxs[cl * 4 + 2] + rxs[cl * 4 + 3];
            float rxc = ((ss > 0.f) ? 1.0f / sqrtf(ss) : 0.0f) * 32.0f;  // fp8 pre-scale
            int b = (int)(((unsigned long long)c * 167773ull) >> 25);    // exact c/200
            int s = c - b * 200;
            size_t rowoff = (size_t)(b * 256 + 25 + s) * 256;
#pragma unroll
            for (int nf = 0; nf < 4; nf++) {
                int a = w * 64 + nf * 16 + l15;
                gp8[rowoff + a] = f2fp8(acc[mf][nf][r] * rta[nf] * rxc);
            }
        }
    }
}

// ================= conv1d(A->A,k=51)+bias+relu+max_a -> m[col], packed N =================
// 8-WAVE (4 row-quarters x 2 col-tiles), A staged ONCE per chunk for both col-tiles.
// R7 structure with the launch-bounds bug fixed: (512,4) -> VGPR cap 128 (R3's proven
// budget; R7's (512,6) capped at 85 and spilled acc to scratch: 7.6GB WRITE, 3ms).
// 2 blocks/CU x 8 waves = 16 waves/CU (same as R3). Grid 800.
__global__ __launch_bounds__(512, 4) void k_conv(const u8* __restrict__ gp8, const u8* __restrict__ ap2,
                                                 const float* __restrict__ cbf, float* __restrict__ mOut) {
    __shared__ __align__(16) u8 smem[49152];     // As 32KB + Bs 16KB (2 tiles)
    u8* As = smem;
    u8* Bs = smem + 32768;
    float* wred = (float*)smem;                  // aliases As AFTER K-loop's final barrier (2KB)
    int t = threadIdx.x, l = t & 63, w = t >> 6;
    int wq = w & 3, ct = w >> 2;
    int c0 = blockIdx.x * 128;

    // B-staging bases: round p stages cols lc = p*64 + (t>>3) (tile p), granule t&7
    size_t srcb[2];
#pragma unroll
    for (int p = 0; p < 2; p++) {
        int lc = p * 64 + (t >> 3);
        int c = c0 + lc;
        int b = (int)(((unsigned long long)c * 167773ull) >> 25);   // exact c/200
        int s = c - b * 200;
        int gsw = (t & 7) ^ ((t >> 3) & 7);
        srcb[p] = (size_t)(b * 256 + s) * 256 + gsw * 16;
    }

    float4_t acc[4][4];
#pragma unroll
    for (int mf = 0; mf < 4; mf++)
#pragma unroll
        for (int nf = 0; nf < 4; nf++) acc[mf][nf] = (float4_t){0.f, 0.f, 0.f, 0.f};

    int l15 = l & 15, kq = l >> 4;

    for (int kb = 0; kb < 102; kb++) {
        // A: 4 linear rounds, 512 threads (ap2 pre-swizzled) — staged once for both tiles
#pragma unroll
        for (int p = 0; p < 4; p++)
            glds16b(ap2 + ((size_t)kb << 15) + (p << 13) + (t << 4), As + (p << 13) + (w << 10));
        // B: 2 rounds (one per tile); chunk byte offset within row = kb*128
        glds16b(gp8 + srcb[0] + ((size_t)kb << 7), Bs + (w << 10));
        glds16b(gp8 + srcb[1] + ((size_t)kb << 7), Bs + 8192 + (w << 10));
        __syncthreads();

        int8v af[4], bfr[4];
#pragma unroll
        for (int mf = 0; mf < 4; mf++) {
            int row = (wq << 6) + (mf << 4) + l15;
            int sw = row & 7;
            const u8* base = As + (row << 7);
            int4 lo = *(const int4*)(base + ((((kq << 1)    ) ^ sw) << 4));
            int4 hi = *(const int4*)(base + ((((kq << 1) | 1) ^ sw) << 4));
            int8v v; v[0]=lo.x; v[1]=lo.y; v[2]=lo.z; v[3]=lo.w; v[4]=hi.x; v[5]=hi.y; v[6]=hi.z; v[7]=hi.w;
            af[mf] = v;
        }
#pragma unroll
        for (int nf = 0; nf < 4; nf++) {
            int row = (nf << 4) + l15;
            int sw = row & 7;
            const u8* base = Bs + (ct << 13) + (row << 7);
            int4 lo = *(const int4*)(base + ((((kq << 1)    ) ^ sw) << 4));
            int4 hi = *(const int4*)(base + ((((kq << 1) | 1) ^ sw) << 4));
            int8v v; v[0]=lo.x; v[1]=lo.y; v[2]=lo.z; v[3]=lo.w; v[4]=hi.x; v[5]=hi.y; v[6]=hi.z; v[7]=hi.w;
            bfr[nf] = v;
        }
#pragma unroll
        for (int mf = 0; mf < 4; mf++)
#pragma unroll
            for (int nf = 0; nf < 4; nf++)
                acc[mf][nf] = __builtin_amdgcn_mfma_scale_f32_16x16x128_f8f6f4(
                    af[mf], bfr[nf], acc[mf][nf], 0, 0, 0, 0x7F7F7F7F, 0, 0x7F7F7F7F);
        __syncthreads();
    }

    // epilogue: undo 2^14 quant scale, +bias, relu (0-init), max over a
    const float SC = 6.103515625e-05f;   // 2^-14
    float vmax[4] = {0.f, 0.f, 0.f, 0.f};
#pragma unroll
    for (int mf = 0; mf < 4; mf++) {
#pragma unroll
        for (int r = 0; r < 4; r++) {
            float bias = cbf[wq * 64 + mf * 16 + kq * 4 + r];
#pragma unroll
            for (int nf = 0; nf < 4; nf++)
                vmax[nf] = fmaxf(vmax[nf], acc[mf][nf][r] * SC + bias);
        }
    }
#pragma unroll
    for (int nf = 0; nf < 4; nf++) {
        vmax[nf] = fmaxf(vmax[nf], __shfl_xor(vmax[nf], 16, 64));
        vmax[nf] = fmaxf(vmax[nf], __shfl_xor(vmax[nf], 32, 64));
    }
    if (l < 16) {
#pragma unroll
        for (int nf = 0; nf < 4; nf++) wred[ct * 256 + wq * 64 + nf * 16 + l] = vmax[nf];
    }
    __syncthreads();
    if (t < 128) {
        int ct2 = t >> 6, col = t & 63;
        float mm = fmaxf(fmaxf(wred[ct2 * 256 + col],       wred[ct2 * 256 + 64 + col]),
                         fmaxf(wred[ct2 * 256 + 128 + col], wred[ct2 * 256 + 192 + col]));
        mOut[c0 + t] = mm;     // packed: col == b*200+s
    }
}

// ================= FUSED tail: masked softmax -> z_s -> logits -> p_t -> r_s =================
__global__ __launch_bounds__(512) void k_tail(const int* __restrict__ x, const float* __restrict__ embf,
                                              const float* __restrict__ Tf, const float* __restrict__ Wwf,
                                              const float* __restrict__ Wbf, const float* __restrict__ mB,
                                              float* __restrict__ o_pt, float* __restrict__ o_zs,
                                              float* __restrict__ o_rs, float* __restrict__ o_ai,
                                              float* __restrict__ o_ptl) {
    __shared__ float aL[200];
    __shared__ int   tokL[200];
    __shared__ __align__(16) float zL[512];
    __shared__ float pL[256];
    __shared__ float lgt[256];
    __shared__ float red[512];
    __shared__ __align__(16) float part[4][512];
    int b = blockIdx.x, t = threadIdx.x;

    float v = 0.f;
    if (t < 200) {
        int tok = x[b * 200 + t];
        tokL[t] = tok;
        v = (tok == PADIDX) ? -1e13f : mB[b * 200 + t];
        red[t] = v;
    }
    __syncthreads();
    if (t < 64) {
        float m = -3.4e38f;
        for (int i = t; i < 200; i += 64) m = fmaxf(m, red[i]);
#pragma unroll
        for (int off = 32; off >= 1; off >>= 1) m = fmaxf(m, __shfl_xor(m, off, 64));
        if (t == 0) red[200] = m;
    }
    __syncthreads();
    float mx = red[200];
    float e = 0.f;
    if (t < 200) { e = expf(v - mx); red[t] = e; }
    __syncthreads();
    if (t < 64) {
        float s = 0.f;
        for (int i = t; i < 200; i += 64) s += red[i];
#pragma unroll
        for (int off = 32; off >= 1; off >>= 1) s += __shfl_xor(s, off, 64);
        if (t == 0) red[201] = s;
    }
    __syncthreads();
    float ainv = 1.0f / red[201];
    if (t < 200) {
        float a = e * ainv;
        aL[t] = a;
        o_ai[b * 200 + t] = a;
    }
    __syncthreads();

    // z_s: 4 lane-groups x 128 lanes, float4 rows, strided s
    {
        int g = t >> 7, l128 = t & 127;
        float4 zp = {0.f, 0.f, 0.f, 0.f};
        for (int s = g; s < 200; s += 4) {
            float as = aL[s];
            float4 rv = ((const float4*)(embf + (size_t)tokL[s] * E_))[l128];
            zp.x += as * rv.x; zp.y += as * rv.y; zp.z += as * rv.z; zp.w += as * rv.w;
        }
        *(float4*)(&part[g][l128 * 4]) = zp;
    }
    __syncthreads();
    {
        float z = part[0][t] + part[1][t] + part[2][t] + part[3][t];
        zL[t] = z;
        o_zs[(size_t)b * 512 + t] = z;
    }
    __syncthreads();

    // logits: (a = t&255, half h = t>>8), each half sums 256 e-dims
    {
        int a = t & 255, h = t >> 8;
        float acc = (h == 0) ? Wbf[a] : 0.f;
        const float4* wr = (const float4*)(Wwf + (size_t)a * E_ + h * 256);
        const float4* zz = (const float4*)(zL + h * 256);
        for (int i = 0; i < 64; i++) {
            float4 w4 = wr[i]; float4 z4 = zz[i];
            acc += w4.x*z4.x + w4.y*z4.y + w4.z*z4.z + w4.w*z4.w;
        }
        red[t] = acc;
    }
    __syncthreads();
    if (t < 256) {
        float lg = red[t] + red[t + 256];
        lgt[t] = lg;
        o_ptl[(size_t)b * 256 + t] = lg;
    }
    __syncthreads();
    if (t < 64) {
        float m = fmaxf(fmaxf(lgt[t], lgt[t + 64]), fmaxf(lgt[t + 128], lgt[t + 192]));
#pragma unroll
        for (int off = 32; off >= 1; off >>= 1) m = fmaxf(m, __shfl_xor(m, off, 64));
        if (t == 0) red[0] = m;
    }
    __syncthreads();
    float lmx = red[0];
    float pe = 0.f;
    if (t < 256) { pe = expf(lgt[t] - lmx); red[256 + t] = pe; }
    __syncthreads();
    if (t < 64) {
        float s = red[256 + t] + red[256 + t + 64] + red[256 + t + 128] + red[256 + t + 192];
#pragma unroll
        for (int off = 32; off >= 1; off >>= 1) s += __shfl_xor(s, off, 64);
        if (t == 0) red[1] = s;
    }
    __syncthreads();
    float pinv = 1.0f / red[1];
    if (t < 256) {
        float p = pe * pinv;
        pL[t] = p;
        o_pt[(size_t)b * 256 + t] = p;
    }
    __syncthreads();

    // r_s: 4 lane-groups x 128 lanes over a-quarters, float4 rows
    {
        int g = t >> 7, l128 = t & 127;
        float4 rp = {0.f, 0.f, 0.f, 0.f};
        for (int a = g * 64; a < g * 64 + 64; a++) {
            float p = pL[a];
            float4 tv = ((const float4*)(Tf + (size_t)a * E_))[l128];
            rp.x += p * tv.x; rp.y += p * tv.y; rp.z += p * tv.z; rp.w += p * tv.w;
        }
        *(float4*)(&part[g][l128 * 4]) = rp;
    }
    __syncthreads();
    o_rs[(size_t)b * 512 + t] = part[0][t] + part[1][t] + part[2][t] + part[3][t];
}

extern "C" void kernel_launch(void* const* d_in, const int* in_sizes, int n_in,
                              void* d_out, int out_size, void* d_ws, size_t ws_size,
                              hipStream_t stream) {
    if (ws_size < WS_NEEDED) return;
    const int*   x    = (const int*)d_in[0];
    const float* embf = (const float*)d_in[1];
    const float* Tf   = (const float*)d_in[2];
    const float* Wwf  = (const float*)d_in[3];
    const float* Wbf  = (const float*)d_in[4];
    const float* cwf  = (const float*)d_in[5];
    const float* cbf  = (const float*)d_in[6];

    char* ws = (char*)d_ws;
    u8*    gp8 = (u8*)(ws + GP8_OFF);
    u8*    ap2 = (u8*)(ws + AP2_OFF);
    u16*   T16 = (u16*)(ws + T16_OFF);
    float* rt  = (float*)(ws + RT_OFF);
    float* mB  = (float*)(ws + M_OFF);

    float* out   = (float*)d_out;
    float* o_pt  = out;                 // [B,A]
    float* o_zs  = out + 131072;        // [B,E]
    float* o_rs  = out + 393216;        // [B,E]
    float* o_ai  = out + 655360;        // [B,S]
    float* o_ptl = out + 757760;        // [B,A]

    k_halo   <<<512,   256, 0, stream>>>(gp8);
    k_cvtT   <<<256,   64,  0, stream>>>(Tf, T16, rt);
    k_prepack<<<256,   256, 0, stream>>>(cwf, ap2);
    k_ggemm  <<<1600,  256, 0, stream>>>(x, embf, T16, rt, gp8);
    k_conv   <<<800,   512, 0, stream>>>(gp8, ap2, cbf, mB);
    k_tail   <<<512,   512, 0, stream>>>(x, embf, Tf, Wwf, Wbf, mB, o_pt, o_zs, o_rs, o_ai, o_ptl);
}

// Round 9
// 611.436 us; speedup vs baseline: 5.3185x; 1.0189x over previous
//
#include <hip/hip_runtime.h>

#define B_  512
#define S_  200
#define E_  512
#define A_  256
#define V_  50000
#define K_  51
#define PADIDX 1

typedef short short8_t __attribute__((ext_vector_type(8)));
typedef float float4_t __attribute__((ext_vector_type(4)));
typedef int   int8v    __attribute__((ext_vector_type(8)));
typedef unsigned short u16;
typedef unsigned int   u32;
typedef unsigned char  u8;

// ---------- f32 -> bf16 RNE (internal staging only) ----------
__device__ __forceinline__ u16 f2b(float f) {
    u32 x = __float_as_uint(f);
    return (u16)((x + 0x7fffu + ((x >> 16) & 1u)) >> 16);
}
// ---------- f32 -> fp8 e4m3 (OCP), via HW cvt ----------
__device__ __forceinline__ u8 f2fp8(float f) {
    int p = __builtin_amdgcn_cvt_pk_fp8_f32(f, 0.f, 0, false);
    return (u8)(p & 0xff);
}

// ---------- async global->LDS, 16B per lane ----------
__device__ __forceinline__ void glds16(const u16* g, short* l) {
    __builtin_amdgcn_global_load_lds(
        (const __attribute__((address_space(1))) unsigned int*)g,
        (__attribute__((address_space(3))) unsigned int*)l, 16, 0, 0);
}
__device__ __forceinline__ void glds16b(const u8* g, const u8* l) {
    __builtin_amdgcn_global_load_lds(
        (const __attribute__((address_space(1))) unsigned int*)g,
        (__attribute__((address_space(3))) unsigned int*)l, 16, 0, 0);
}

// ---------- workspace offsets (bytes); total guard 76,628,992 (proven) ----------
#define GP8_OFF   0ull
#define GP8_BYTES 33587200ull          // 131072 rows * 256 fp8 + 32KB slack
#define AP2_OFF   33587200ull          // packed+swizzled conv weights: 102*32768 fp8
#define RT_OFF    36929536ull          // 1/||T_a||   (256 f32)
#define RX_OFF    36930560ull          // (unused now)
#define M_OFF     37340160ull          // m[b,s]      (102400 f32)
#define T16_OFF   37749760ull          // T in bf16 (512KB)
#define WS_NEEDED 76628992ull

// ================= zero gp8 halo rows: b*256+[0,25) and b*256+[225,250) =================
__global__ __launch_bounds__(256) void k_halo(u8* __restrict__ gp8) {
    int b = blockIdx.x, t = threadIdx.x;
    size_t base = (size_t)b << 16;                 // 256 rows * 256 B
    float4 z = {0.f, 0.f, 0.f, 0.f};
#pragma unroll
    for (int rdx = 0; rdx < 4; rdx++) {
        int q = rdx * 256 + t;
        if (q < 400)      *(float4*)(gp8 + base + (size_t)q * 16) = z;                 // rows [0,25)
        else if (q < 800) *(float4*)(gp8 + base + 57600 + (size_t)(q - 400) * 16) = z; // rows [225,250)
    }
}

// ================= T (f32) -> bf16  +  1/||T_a||  (merged) =================
__global__ __launch_bounds__(64) void k_cvtT(const float* __restrict__ Tf, u16* __restrict__ T16,
                                             float* __restrict__ rt) {
    int a = blockIdx.x, l = threadIdx.x;
    const float* src = Tf + (size_t)a * E_ + l * 8;
    float4 d0 = *(const float4*)(src);
    float4 d1 = *(const float4*)(src + 4);
    ushort4 r0, r1;
    r0.x = f2b(d0.x); r0.y = f2b(d0.y); r0.z = f2b(d0.z); r0.w = f2b(d0.w);
    r1.x = f2b(d1.x); r1.y = f2b(d1.y); r1.z = f2b(d1.z); r1.w = f2b(d1.w);
    *(ushort4*)(T16 + (size_t)a * E_ + l * 8)     = r0;
    *(ushort4*)(T16 + (size_t)a * E_ + l * 8 + 4) = r1;
    float s = d0.x*d0.x + d0.y*d0.y + d0.z*d0.z + d0.w*d0.w
            + d1.x*d1.x + d1.y*d1.y + d1.z*d1.z + d1.w*d1.w;
#pragma unroll
    for (int off = 32; off >= 1; off >>= 1) s += __shfl_xor(s, off, 64);
    if (l == 0) rt[a] = (s > 0.f) ? 1.0f / sqrtf(s) : 0.0f;
}

// ========= pack conv_w (f32) -> ap2[kb][a][granule-swizzled 128B] fp8, scaled x512 =========
// COALESCED (proven R6): one block per output row r; linear float4 reads, LDS transpose,
// line-coalesced 16B stores. Bijection: kk = tap*256+i; kb=kk>>7; j=i&15; lg=(i>>4)&7;
// gslot = lg^(r&7); dst = ap2[kb*32768 + r*128 + gslot*16 + j] = fp8(cwf[r][i][tap]*512).
__global__ __launch_bounds__(256) void k_prepack(const float* __restrict__ cwf, u8* __restrict__ ap2) {
    __shared__ __align__(16) u8 L[13184];
    int r = blockIdx.x, t = threadIdx.x;
    int rs = r & 7;
    const float* src = cwf + (size_t)r * (A_ * K_);

    for (int q = 0; q < 13; q++) {
        int e4 = q * 256 + t;
        if (e4 < 3264) {
            float4 v = ((const float4*)src)[e4];
            float vals[4] = {v.x, v.y, v.z, v.w};
            int id0 = e4 * 4;
#pragma unroll
            for (int u = 0; u < 4; u++) {
                int id  = id0 + u;
                int i   = (int)(((unsigned long long)id * 84215046ull) >> 32);  // exact id/51
                int tap = id - i * 51;
                int kb  = tap * 2 + (i >> 7);
                int j   = i & 15;
                int lg  = (i >> 4) & 7;
                int off7 = ((lg ^ rs) << 4) | j;
                L[kb * 128 + (off7 ^ ((kb & 7) << 4))] = f2fp8(vals[u] * 512.0f);
            }
        }
    }
    __syncthreads();
#pragma unroll
    for (int q = 0; q < 4; q++) {
        int o16 = q * 256 + t;
        if (o16 < 816) {
            int byteo = o16 * 16;
            int kb = byteo >> 7;
            int p  = byteo & 127;
            int4 d = *(const int4*)(L + (byteo & ~127) + (p ^ ((kb & 7) << 4)));
            *(int4*)(ap2 + (size_t)kb * 32768 + (size_t)r * 128 + p) = d;
        }
    }
}

// ================= g = cosine(T, emb[x]) -> gp8[(b*256+25+s)*256 + a] fp8 (x32) =================
// rx (1/||xx_c||) computed IN-KERNEL (R5-proven).
__global__ __launch_bounds__(256) void k_ggemm(const int* __restrict__ x, const float* __restrict__ embf,
                                               const u16* __restrict__ T16, const float* __restrict__ rt,
                                               u8* __restrict__ gp8) {
    __shared__ __align__(16) short Xs[64 * 32];
    __shared__ __align__(16) short Ts[256 * 32];
    int t = threadIdx.x, l = t & 63, w = t >> 6;
    int c0 = blockIdx.x * 64;
    int crow  = t >> 2;
    int xslog = (t & 3) ^ ((crow >> 1) & 3);
    size_t xbase = (size_t)x[c0 + crow] * E_;

    float4_t acc[4][4];
#pragma unroll
    for (int mf = 0; mf < 4; mf++)
#pragma unroll
        for (int nf = 0; nf < 4; nf++) acc[mf][nf] = (float4_t){0.f, 0.f, 0.f, 0.f};

    float ssq = 0.f;                                 // partial ||xx_row||^2 (8 elems/iter)

    for (int ec = 0; ec < 16; ec++) {
        int e0 = ec * 32;
        {
            const float* src = embf + xbase + e0 + xslog * 8;
            float4 f0 = *(const float4*)(src);
            float4 f1 = *(const float4*)(src + 4);
            ssq += f0.x*f0.x + f0.y*f0.y + f0.z*f0.z + f0.w*f0.w
                 + f1.x*f1.x + f1.y*f1.y + f1.z*f1.z + f1.w*f1.w;
            short8_t pk;
            pk[0] = (short)f2b(f0.x); pk[1] = (short)f2b(f0.y);
            pk[2] = (short)f2b(f0.z); pk[3] = (short)f2b(f0.w);
            pk[4] = (short)f2b(f1.x); pk[5] = (short)f2b(f1.y);
            pk[6] = (short)f2b(f1.z); pk[7] = (short)f2b(f1.w);
            *(short8_t*)(Xs + t * 8) = pk;
        }
#pragma unroll
        for (int p = 0; p < 4; p++) {
            int idx  = p * 256 + t;
            int arow = idx >> 2;
            int slog = (idx & 3) ^ ((arow >> 1) & 3);
            glds16(T16 + (size_t)arow * E_ + e0 + slog * 8, Ts + (p * 256 + w * 64) * 8);
        }
        __syncthreads();
        int l15 = l & 15, q = l >> 4;
        short8_t af[4], bf[4];
#pragma unroll
        for (int mf = 0; mf < 4; mf++) {
            int row = mf * 16 + l15;
            int kph = q ^ ((row >> 1) & 3);
            af[mf] = *(const short8_t*)(Xs + row * 32 + kph * 8);
        }
#pragma unroll
        for (int nf = 0; nf < 4; nf++) {
            int row = w * 64 + nf * 16 + l15;
            int kph = q ^ ((row >> 1) & 3);
            bf[nf] = *(const short8_t*)(Ts + row * 32 + kph * 8);
        }
#pragma unroll
        for (int mf = 0; mf < 4; mf++)
#pragma unroll
            for (int nf = 0; nf < 4; nf++)
                acc[mf][nf] = __builtin_amdgcn_mfma_f32_16x16x32_bf16(af[mf], bf[nf], acc[mf][nf], 0, 0, 0);
        __syncthreads();
    }

    // reduce 4 ssq partials per row through dead Xs
    float* rxs = (float*)Xs;
    rxs[t] = ssq;                        // t = crow*4 + (t&3)
    __syncthreads();

    int l15 = l & 15, q = l >> 4;
    float rta[4];
#pragma unroll
    for (int nf = 0; nf < 4; nf++) rta[nf] = rt[w * 64 + nf * 16 + l15];
#pragma unroll
    for (int mf = 0; mf < 4; mf++) {
#pragma unroll
        for (int r = 0; r < 4; r++) {
            int cl = mf * 16 + q * 4 + r;
            int c = c0 + cl;
            float ss = rxs[cl * 4] + rxs[cl * 4 + 1] + rxs[cl * 4 + 2] + rxs[cl * 4 + 3];
            float rxc = ((ss > 0.f) ? 1.0f / sqrtf(ss) : 0.0f) * 32.0f;  // fp8 pre-scale
            int b = (int)(((unsigned long long)c * 167773ull) >> 25);    // exact c/200
            int s = c - b * 200;
            size_t rowoff = (size_t)(b * 256 + 25 + s) * 256;
#pragma unroll
            for (int nf = 0; nf < 4; nf++) {
                int a = w * 64 + nf * 16 + l15;
                gp8[rowoff + a] = f2fp8(acc[mf][nf][r] * rta[nf] * rxc);
            }
        }
    }
}

// ================= conv1d(A->A,k=51)+bias+relu+max_a -> m[col], packed N =================
// 8-WAVE (4 row-quarters x 2 col-tiles), A staged once per chunk (R8-proven, 335us).
// R9 change (T3-minimum reorder): per chunk, STAGE issue moved BETWEEN the ds_reads and
// the MFMA cluster -> stage's L2 latency hides under ~550 cyc of MFMA instead of being
// drained cold at the barrier. Same 2 barriers/chunk, same LDS/regs/occupancy.
//   prologue: STAGE(0); bar
//   loop kb:  reads(buf) -> bar1 (ds_reads drained, LDS safe) -> STAGE(kb+1) -> MFMA -> bar2
__global__ __launch_bounds__(512, 4) void k_conv(const u8* __restrict__ gp8, const u8* __restrict__ ap2,
                                                 const float* __restrict__ cbf, float* __restrict__ mOut) {
    __shared__ __align__(16) u8 smem[49152];     // As 32KB + Bs 16KB (2 tiles)
    u8* As = smem;
    u8* Bs = smem + 32768;
    float* wred = (float*)smem;                  // aliases As AFTER K-loop's final barrier (2KB)
    int t = threadIdx.x, l = t & 63, w = t >> 6;
    int wq = w & 3, ct = w >> 2;
    int c0 = blockIdx.x * 128;

    // B-staging bases: round p stages cols lc = p*64 + (t>>3) (tile p), granule t&7
    size_t srcb[2];
#pragma unroll
    for (int p = 0; p < 2; p++) {
        int lc = p * 64 + (t >> 3);
        int c = c0 + lc;
        int b = (int)(((unsigned long long)c * 167773ull) >> 25);   // exact c/200
        int s = c - b * 200;
        int gsw = (t & 7) ^ ((t >> 3) & 7);
        srcb[p] = (size_t)(b * 256 + s) * 256 + gsw * 16;
    }

    float4_t acc[4][4];
#pragma unroll
    for (int mf = 0; mf < 4; mf++)
#pragma unroll
        for (int nf = 0; nf < 4; nf++) acc[mf][nf] = (float4_t){0.f, 0.f, 0.f, 0.f};

    int l15 = l & 15, kq = l >> 4;

#define STAGE(kb_) do {                                                                   \
    _Pragma("unroll") for (int p = 0; p < 4; p++)                                         \
        glds16b(ap2 + (((size_t)(kb_)) << 15) + (p << 13) + (t << 4),                     \
                As + (p << 13) + (w << 10));                                              \
    glds16b(gp8 + srcb[0] + (((size_t)(kb_)) << 7), Bs + (w << 10));                      \
    glds16b(gp8 + srcb[1] + (((size_t)(kb_)) << 7), Bs + 8192 + (w << 10));               \
    } while (0)

    // prologue: chunk 0 staged
    STAGE(0);
    __syncthreads();

    for (int kb = 0; kb < 102; kb++) {
        int8v af[4], bfr[4];
#pragma unroll
        for (int mf = 0; mf < 4; mf++) {
            int row = (wq << 6) + (mf << 4) + l15;
            int sw = row & 7;
            const u8* base = As + (row << 7);
            int4 lo = *(const int4*)(base + ((((kq << 1)    ) ^ sw) << 4));
            int4 hi = *(const int4*)(base + ((((kq << 1) | 1) ^ sw) << 4));
            int8v v; v[0]=lo.x; v[1]=lo.y; v[2]=lo.z; v[3]=lo.w; v[4]=hi.x; v[5]=hi.y; v[6]=hi.z; v[7]=hi.w;
            af[mf] = v;
        }
#pragma unroll
        for (int nf = 0; nf < 4; nf++) {
            int row = (nf << 4) + l15;
            int sw = row & 7;
            const u8* base = Bs + (ct << 13) + (row << 7);
            int4 lo = *(const int4*)(base + ((((kq << 1)    ) ^ sw) << 4));
            int4 hi = *(const int4*)(base + ((((kq << 1) | 1) ^ sw) << 4));
            int8v v; v[0]=lo.x; v[1]=lo.y; v[2]=lo.z; v[3]=lo.w; v[4]=hi.x; v[5]=hi.y; v[6]=hi.z; v[7]=hi.w;
            bfr[nf] = v;
        }
        __syncthreads();                 // ds_reads drained -> LDS safe to overwrite
        if (kb + 1 < 102) STAGE(kb + 1); // stage latency hides under the MFMA cluster
#pragma unroll
        for (int mf = 0; mf < 4; mf++)
#pragma unroll
            for (int nf = 0; nf < 4; nf++)
                acc[mf][nf] = __builtin_amdgcn_mfma_scale_f32_16x16x128_f8f6f4(
                    af[mf], bfr[nf], acc[mf][nf], 0, 0, 0, 0x7F7F7F7F, 0, 0x7F7F7F7F);
        __syncthreads();                 // stage drained -> next iter reads new chunk
    }
#undef STAGE

    // epilogue: undo 2^14 quant scale, +bias, relu (0-init), max over a
    const float SC = 6.103515625e-05f;   // 2^-14
    float vmax[4] = {0.f, 0.f, 0.f, 0.f};
#pragma unroll
    for (int mf = 0; mf < 4; mf++) {
#pragma unroll
        for (int r = 0; r < 4; r++) {
            float bias = cbf[wq * 64 + mf * 16 + kq * 4 + r];
#pragma unroll
            for (int nf = 0; nf < 4; nf++)
                vmax[nf] = fmaxf(vmax[nf], acc[mf][nf][r] * SC + bias);
        }
    }
#pragma unroll
    for (int nf = 0; nf < 4; nf++) {
        vmax[nf] = fmaxf(vmax[nf], __shfl_xor(vmax[nf], 16, 64));
        vmax[nf] = fmaxf(vmax[nf], __shfl_xor(vmax[nf], 32, 64));
    }
    if (l < 16) {
#pragma unroll
        for (int nf = 0; nf < 4; nf++) wred[ct * 256 + wq * 64 + nf * 16 + l] = vmax[nf];
    }
    __syncthreads();
    if (t < 128) {
        int ct2 = t >> 6, col = t & 63;
        float mm = fmaxf(fmaxf(wred[ct2 * 256 + col],       wred[ct2 * 256 + 64 + col]),
                         fmaxf(wred[ct2 * 256 + 128 + col], wred[ct2 * 256 + 192 + col]));
        mOut[c0 + t] = mm;     // packed: col == b*200+s
    }
}

// ================= FUSED tail: masked softmax -> z_s -> logits -> p_t -> r_s =================
__global__ __launch_bounds__(512) void k_tail(const int* __restrict__ x, const float* __restrict__ embf,
                                              const float* __restrict__ Tf, const float* __restrict__ Wwf,
                                              const float* __restrict__ Wbf, const float* __restrict__ mB,
                                              float* __restrict__ o_pt, float* __restrict__ o_zs,
                                              float* __restrict__ o_rs, float* __restrict__ o_ai,
                                              float* __restrict__ o_ptl) {
    __shared__ float aL[200];
    __shared__ int   tokL[200];
    __shared__ __align__(16) float zL[512];
    __shared__ float pL[256];
    __shared__ float lgt[256];
    __shared__ float red[512];
    __shared__ __align__(16) float part[4][512];
    int b = blockIdx.x, t = threadIdx.x;

    float v = 0.f;
    if (t < 200) {
        int tok = x[b * 200 + t];
        tokL[t] = tok;
        v = (tok == PADIDX) ? -1e13f : mB[b * 200 + t];
        red[t] = v;
    }
    __syncthreads();
    if (t < 64) {
        float m = -3.4e38f;
        for (int i = t; i < 200; i += 64) m = fmaxf(m, red[i]);
#pragma unroll
        for (int off = 32; off >= 1; off >>= 1) m = fmaxf(m, __shfl_xor(m, off, 64));
        if (t == 0) red[200] = m;
    }
    __syncthreads();
    float mx = red[200];
    float e = 0.f;
    if (t < 200) { e = expf(v - mx); red[t] = e; }
    __syncthreads();
    if (t < 64) {
        float s = 0.f;
        for (int i = t; i < 200; i += 64) s += red[i];
#pragma unroll
        for (int off = 32; off >= 1; off >>= 1) s += __shfl_xor(s, off, 64);
        if (t == 0) red[201] = s;
    }
    __syncthreads();
    float ainv = 1.0f / red[201];
    if (t < 200) {
        float a = e * ainv;
        aL[t] = a;
        o_ai[b * 200 + t] = a;
    }
    __syncthreads();

    // z_s: 4 lane-groups x 128 lanes, float4 rows, strided s
    {
        int g = t >> 7, l128 = t & 127;
        float4 zp = {0.f, 0.f, 0.f, 0.f};
        for (int s = g; s < 200; s += 4) {
            float as = aL[s];
            float4 rv = ((const float4*)(embf + (size_t)tokL[s] * E_))[l128];
            zp.x += as * rv.x; zp.y += as * rv.y; zp.z += as * rv.z; zp.w += as * rv.w;
        }
        *(float4*)(&part[g][l128 * 4]) = zp;
    }
    __syncthreads();
    {
        float z = part[0][t] + part[1][t] + part[2][t] + part[3][t];
        zL[t] = z;
        o_zs[(size_t)b * 512 + t] = z;
    }
    __syncthreads();

    // logits: (a = t&255, half h = t>>8), each half sums 256 e-dims
    {
        int a = t & 255, h = t >> 8;
        float acc = (h == 0) ? Wbf[a] : 0.f;
        const float4* wr = (const float4*)(Wwf + (size_t)a * E_ + h * 256);
        const float4* zz = (const float4*)(zL + h * 256);
        for (int i = 0; i < 64; i++) {
            float4 w4 = wr[i]; float4 z4 = zz[i];
            acc += w4.x*z4.x + w4.y*z4.y + w4.z*z4.z + w4.w*z4.w;
        }
        red[t] = acc;
    }
    __syncthreads();
    if (t < 256) {
        float lg = red[t] + red[t + 256];
        lgt[t] = lg;
        o_ptl[(size_t)b * 256 + t] = lg;
    }
    __syncthreads();
    if (t < 64) {
        float m = fmaxf(fmaxf(lgt[t], lgt[t + 64]), fmaxf(lgt[t + 128], lgt[t + 192]));
#pragma unroll
        for (int off = 32; off >= 1; off >>= 1) m = fmaxf(m, __shfl_xor(m, off, 64));
        if (t == 0) red[0] = m;
    }
    __syncthreads();
    float lmx = red[0];
    float pe = 0.f;
    if (t < 256) { pe = expf(lgt[t] - lmx); red[256 + t] = pe; }
    __syncthreads();
    if (t < 64) {
        float s = red[256 + t] + red[256 + t + 64] + red[256 + t + 128] + red[256 + t + 192];
#pragma unroll
        for (int off = 32; off >= 1; off >>= 1) s += __shfl_xor(s, off, 64);
        if (t == 0) red[1] = s;
    }
    __syncthreads();
    float pinv = 1.0f / red[1];
    if (t < 256) {
        float p = pe * pinv;
        pL[t] = p;
        o_pt[(size_t)b * 256 + t] = p;
    }
    __syncthreads();

    // r_s: 4 lane-groups x 128 lanes over a-quarters, float4 rows
    {
        int g = t >> 7, l128 = t & 127;
        float4 rp = {0.f, 0.f, 0.f, 0.f};
        for (int a = g * 64; a < g * 64 + 64; a++) {
            float p = pL[a];
            float4 tv = ((const float4*)(Tf + (size_t)a * E_))[l128];
            rp.x += p * tv.x; rp.y += p * tv.y; rp.z += p * tv.z; rp.w += p * tv.w;
        }
        *(float4*)(&part[g][l128 * 4]) = rp;
    }
    __syncthreads();
    o_rs[(size_t)b * 512 + t] = part[0][t] + part[1][t] + part[2][t] + part[3][t];
}

extern "C" void kernel_launch(void* const* d_in, const int* in_sizes, int n_in,
                              void* d_out, int out_size, void* d_ws, size_t ws_size,
                              hipStream_t stream) {
    if (ws_size < WS_NEEDED) return;
    const int*   x    = (const int*)d_in[0];
    const float* embf = (const float*)d_in[1];
    const float* Tf   = (const float*)d_in[2];
    const float* Wwf  = (const float*)d_in[3];
    const float* Wbf  = (const float*)d_in[4];
    const float* cwf  = (const float*)d_in[5];
    const float* cbf  = (const float*)d_in[6];

    char* ws = (char*)d_ws;
    u8*    gp8 = (u8*)(ws + GP8_OFF);
    u8*    ap2 = (u8*)(ws + AP2_OFF);
    u16*   T16 = (u16*)(ws + T16_OFF);
    float* rt  = (float*)(ws + RT_OFF);
    float* mB  = (float*)(ws + M_OFF);

    float* out   = (float*)d_out;
    float* o_pt  = out;                 // [B,A]
    float* o_zs  = out + 131072;        // [B,E]
    float* o_rs  = out + 393216;        // [B,E]
    float* o_ai  = out + 655360;        // [B,S]
    float* o_ptl = out + 757760;        // [B,A]

    k_halo   <<<512,   256, 0, stream>>>(gp8);
    k_cvtT   <<<256,   64,  0, stream>>>(Tf, T16, rt);
    k_prepack<<<256,   256, 0, stream>>>(cwf, ap2);
    k_ggemm  <<<1600,  256, 0, stream>>>(x, embf, T16, rt, gp8);
    k_conv   <<<800,   512, 0, stream>>>(gp8, ap2, cbf, mB);
    k_tail   <<<512,   512, 0, stream>>>(x, embf, Tf, Wwf, Wbf, mB, o_pt, o_zs, o_rs, o_ai, o_ptl);
}

// Round 10
// 594.968 us; speedup vs baseline: 5.4657x; 1.0277x over previous
//
#include <hip/hip_runtime.h>

#define B_  512
#define S_  200
#define E_  512
#define A_  256
#define V_  50000
#define K_  51
#define PADIDX 1

typedef short short8_t __attribute__((ext_vector_type(8)));
typedef float float4_t __attribute__((ext_vector_type(4)));
typedef int   int8v    __attribute__((ext_vector_type(8)));
typedef unsigned short u16;
typedef unsigned int   u32;
typedef unsigned char  u8;

// ---------- f32 -> bf16 RNE (internal staging only) ----------
__device__ __forceinline__ u16 f2b(float f) {
    u32 x = __float_as_uint(f);
    return (u16)((x + 0x7fffu + ((x >> 16) & 1u)) >> 16);
}
// ---------- f32 -> fp8 e4m3 (OCP), via HW cvt ----------
__device__ __forceinline__ u8 f2fp8(float f) {
    int p = __builtin_amdgcn_cvt_pk_fp8_f32(f, 0.f, 0, false);
    return (u8)(p & 0xff);
}

// ---------- async global->LDS, 16B per lane ----------
__device__ __forceinline__ void glds16(const u16* g, short* l) {
    __builtin_amdgcn_global_load_lds(
        (const __attribute__((address_space(1))) unsigned int*)g,
        (__attribute__((address_space(3))) unsigned int*)l, 16, 0, 0);
}
__device__ __forceinline__ void glds16b(const u8* g, const u8* l) {
    __builtin_amdgcn_global_load_lds(
        (const __attribute__((address_space(1))) unsigned int*)g,
        (__attribute__((address_space(3))) unsigned int*)l, 16, 0, 0);
}

// ---------- workspace offsets (bytes); total guard 76,628,992 (proven) ----------
#define GP8_OFF   0ull
#define GP8_BYTES 33587200ull          // 131072 rows * 256 fp8 + 32KB slack
#define AP2_OFF   33587200ull          // packed+swizzled conv weights: 102*32768 fp8
#define RT_OFF    36929536ull          // 1/||T_a||   (256 f32)
#define RX_OFF    36930560ull          // (unused now)
#define M_OFF     37340160ull          // m[b,s]      (102400 f32)
#define T16_OFF   37749760ull          // T in bf16 (512KB)
#define WS_NEEDED 76628992ull

// ================= zero gp8 halo rows: b*256+[0,25) and b*256+[225,250) =================
__global__ __launch_bounds__(256) void k_halo(u8* __restrict__ gp8) {
    int b = blockIdx.x, t = threadIdx.x;
    size_t base = (size_t)b << 16;                 // 256 rows * 256 B
    float4 z = {0.f, 0.f, 0.f, 0.f};
#pragma unroll
    for (int rdx = 0; rdx < 4; rdx++) {
        int q = rdx * 256 + t;
        if (q < 400)      *(float4*)(gp8 + base + (size_t)q * 16) = z;                 // rows [0,25)
        else if (q < 800) *(float4*)(gp8 + base + 57600 + (size_t)(q - 400) * 16) = z; // rows [225,250)
    }
}

// ================= T (f32) -> bf16  +  1/||T_a||  (merged) =================
__global__ __launch_bounds__(64) void k_cvtT(const float* __restrict__ Tf, u16* __restrict__ T16,
                                             float* __restrict__ rt) {
    int a = blockIdx.x, l = threadIdx.x;
    const float* src = Tf + (size_t)a * E_ + l * 8;
    float4 d0 = *(const float4*)(src);
    float4 d1 = *(const float4*)(src + 4);
    ushort4 r0, r1;
    r0.x = f2b(d0.x); r0.y = f2b(d0.y); r0.z = f2b(d0.z); r0.w = f2b(d0.w);
    r1.x = f2b(d1.x); r1.y = f2b(d1.y); r1.z = f2b(d1.z); r1.w = f2b(d1.w);
    *(ushort4*)(T16 + (size_t)a * E_ + l * 8)     = r0;
    *(ushort4*)(T16 + (size_t)a * E_ + l * 8 + 4) = r1;
    float s = d0.x*d0.x + d0.y*d0.y + d0.z*d0.z + d0.w*d0.w
            + d1.x*d1.x + d1.y*d1.y + d1.z*d1.z + d1.w*d1.w;
#pragma unroll
    for (int off = 32; off >= 1; off >>= 1) s += __shfl_xor(s, off, 64);
    if (l == 0) rt[a] = (s > 0.f) ? 1.0f / sqrtf(s) : 0.0f;
}

// ========= pack conv_w (f32) -> ap2[kb][a][granule-swizzled 128B] fp8, scaled x512 =========
// COALESCED (proven R6): one block per output row r; linear float4 reads, LDS transpose,
// line-coalesced 16B stores. Bijection: kk = tap*256+i; kb=kk>>7; j=i&15; lg=(i>>4)&7;
// gslot = lg^(r&7); dst = ap2[kb*32768 + r*128 + gslot*16 + j] = fp8(cwf[r][i][tap]*512).
__global__ __launch_bounds__(256) void k_prepack(const float* __restrict__ cwf, u8* __restrict__ ap2) {
    __shared__ __align__(16) u8 L[13184];
    int r = blockIdx.x, t = threadIdx.x;
    int rs = r & 7;
    const float* src = cwf + (size_t)r * (A_ * K_);

    for (int q = 0; q < 13; q++) {
        int e4 = q * 256 + t;
        if (e4 < 3264) {
            float4 v = ((const float4*)src)[e4];
            float vals[4] = {v.x, v.y, v.z, v.w};
            int id0 = e4 * 4;
#pragma unroll
            for (int u = 0; u < 4; u++) {
                int id  = id0 + u;
                int i   = (int)(((unsigned long long)id * 84215046ull) >> 32);  // exact id/51
                int tap = id - i * 51;
                int kb  = tap * 2 + (i >> 7);
                int j   = i & 15;
                int lg  = (i >> 4) & 7;
                int off7 = ((lg ^ rs) << 4) | j;
                L[kb * 128 + (off7 ^ ((kb & 7) << 4))] = f2fp8(vals[u] * 512.0f);
            }
        }
    }
    __syncthreads();
#pragma unroll
    for (int q = 0; q < 4; q++) {
        int o16 = q * 256 + t;
        if (o16 < 816) {
            int byteo = o16 * 16;
            int kb = byteo >> 7;
            int p  = byteo & 127;
            int4 d = *(const int4*)(L + (byteo & ~127) + (p ^ ((kb & 7) << 4)));
            *(int4*)(ap2 + (size_t)kb * 32768 + (size_t)r * 128 + p) = d;
        }
    }
}

// ================= g = cosine(T, emb[x]) -> gp8[(b*256+25+s)*256 + a] fp8 (x32) =================
// 8-WAVE / 128-col version (R8-conv recipe applied to ggemm): 512 threads =
// (2 col-halves ct) x (4 a-quarters wq). T-tile staging + barrier periods amortize over
// 2x output; X gather unchanged (each token row still read once). acc[4][4] = 64 VGPR/wave,
// launch_bounds (512,4) = 128 cap (proven R8 profile). LDS: Xs 8KB + Ts 16KB = 24KB.
__global__ __launch_bounds__(512, 4) void k_ggemm(const int* __restrict__ x, const float* __restrict__ embf,
                                                  const u16* __restrict__ T16, const float* __restrict__ rt,
                                                  u8* __restrict__ gp8) {
    __shared__ __align__(16) short Xs[128 * 32];   // 8 KB
    __shared__ __align__(16) short Ts[256 * 32];   // 16 KB
    int t = threadIdx.x, l = t & 63, w = t >> 6;
    int wq = w & 3, ct = w >> 2;
    int c0 = blockIdx.x * 128;
    int crow  = t >> 2;                            // 128 rows, 4 threads/row
    int xslog = (t & 3) ^ ((crow >> 1) & 3);
    size_t xbase = (size_t)x[c0 + crow] * E_;

    float4_t acc[4][4];
#pragma unroll
    for (int mf = 0; mf < 4; mf++)
#pragma unroll
        for (int nf = 0; nf < 4; nf++) acc[mf][nf] = (float4_t){0.f, 0.f, 0.f, 0.f};

    float ssq = 0.f;                               // partial ||xx_row||^2 (8 elems/iter)

    for (int ec = 0; ec < 16; ec++) {
        int e0 = ec * 32;
        {
            const float* src = embf + xbase + e0 + xslog * 8;
            float4 f0 = *(const float4*)(src);
            float4 f1 = *(const float4*)(src + 4);
            ssq += f0.x*f0.x + f0.y*f0.y + f0.z*f0.z + f0.w*f0.w
                 + f1.x*f1.x + f1.y*f1.y + f1.z*f1.z + f1.w*f1.w;
            short8_t pk;
            pk[0] = (short)f2b(f0.x); pk[1] = (short)f2b(f0.y);
            pk[2] = (short)f2b(f0.z); pk[3] = (short)f2b(f0.w);
            pk[4] = (short)f2b(f1.x); pk[5] = (short)f2b(f1.y);
            pk[6] = (short)f2b(f1.z); pk[7] = (short)f2b(f1.w);
            *(short8_t*)(Xs + t * 8) = pk;
        }
#pragma unroll
        for (int p = 0; p < 2; p++) {              // 2 rounds x 512 threads cover 256 rows x 4 slots
            int idx  = p * 512 + t;
            int arow = idx >> 2;
            int slog = (idx & 3) ^ ((arow >> 1) & 3);
            glds16(T16 + (size_t)arow * E_ + e0 + slog * 8, Ts + (p * 512 + w * 64) * 8);
        }
        __syncthreads();
        int l15 = l & 15, q = l >> 4;
        short8_t af[4], bf[4];
#pragma unroll
        for (int mf = 0; mf < 4; mf++) {
            int row = (ct << 6) + (mf << 4) + l15;
            int kph = q ^ ((row >> 1) & 3);
            af[mf] = *(const short8_t*)(Xs + row * 32 + kph * 8);
        }
#pragma unroll
        for (int nf = 0; nf < 4; nf++) {
            int row = (wq << 6) + (nf << 4) + l15;
            int kph = q ^ ((row >> 1) & 3);
            bf[nf] = *(const short8_t*)(Ts + row * 32 + kph * 8);
        }
#pragma unroll
        for (int mf = 0; mf < 4; mf++)
#pragma unroll
            for (int nf = 0; nf < 4; nf++)
                acc[mf][nf] = __builtin_amdgcn_mfma_f32_16x16x32_bf16(af[mf], bf[nf], acc[mf][nf], 0, 0, 0);
        __syncthreads();
    }

    // reduce 4 ssq partials per row through dead Xs (512 floats = 2KB <= 8KB)
    float* rxs = (float*)Xs;
    rxs[t] = ssq;                        // t = crow*4 + (t&3)
    __syncthreads();

    int l15 = l & 15, q = l >> 4;
    float rta[4];
#pragma unroll
    for (int nf = 0; nf < 4; nf++) rta[nf] = rt[wq * 64 + nf * 16 + l15];
#pragma unroll
    for (int mf = 0; mf < 4; mf++) {
#pragma unroll
        for (int r = 0; r < 4; r++) {
            int cl = (ct << 6) + mf * 16 + q * 4 + r;
            int c = c0 + cl;
            float ss = rxs[cl * 4] + rxs[cl * 4 + 1] + rxs[cl * 4 + 2] + rxs[cl * 4 + 3];
            float rxc = ((ss > 0.f) ? 1.0f / sqrtf(ss) : 0.0f) * 32.0f;  // fp8 pre-scale
            int b = (int)(((unsigned long long)c * 167773ull) >> 25);    // exact c/200
            int s = c - b * 200;
            size_t rowoff = (size_t)(b * 256 + 25 + s) * 256;
#pragma unroll
            for (int nf = 0; nf < 4; nf++) {
                int a = wq * 64 + nf * 16 + l15;
                gp8[rowoff + a] = f2fp8(acc[mf][nf][r] * rta[nf] * rxc);
            }
        }
    }
}

// ================= conv1d(A->A,k=51)+bias+relu+max_a -> m[col], packed N =================
// FROZEN at R8 (335us proven): 8-wave (4 row-quarters x 2 col-tiles), A staged once per
// chunk, stage-at-top 2-barrier loop, launch_bounds (512,4). R9's reorder regressed (342).
__global__ __launch_bounds__(512, 4) void k_conv(const u8* __restrict__ gp8, const u8* __restrict__ ap2,
                                                 const float* __restrict__ cbf, float* __restrict__ mOut) {
    __shared__ __align__(16) u8 smem[49152];     // As 32KB + Bs 16KB (2 tiles)
    u8* As = smem;
    u8* Bs = smem + 32768;
    float* wred = (float*)smem;                  // aliases As AFTER K-loop's final barrier (2KB)
    int t = threadIdx.x, l = t & 63, w = t >> 6;
    int wq = w & 3, ct = w >> 2;
    int c0 = blockIdx.x * 128;

    // B-staging bases: round p stages cols lc = p*64 + (t>>3) (tile p), granule t&7
    size_t srcb[2];
#pragma unroll
    for (int p = 0; p < 2; p++) {
        int lc = p * 64 + (t >> 3);
        int c = c0 + lc;
        int b = (int)(((unsigned long long)c * 167773ull) >> 25);   // exact c/200
        int s = c - b * 200;
        int gsw = (t & 7) ^ ((t >> 3) & 7);
        srcb[p] = (size_t)(b * 256 + s) * 256 + gsw * 16;
    }

    float4_t acc[4][4];
#pragma unroll
    for (int mf = 0; mf < 4; mf++)
#pragma unroll
        for (int nf = 0; nf < 4; nf++) acc[mf][nf] = (float4_t){0.f, 0.f, 0.f, 0.f};

    int l15 = l & 15, kq = l >> 4;

    for (int kb = 0; kb < 102; kb++) {
        // A: 4 linear rounds, 512 threads (ap2 pre-swizzled) — staged once for both tiles
#pragma unroll
        for (int p = 0; p < 4; p++)
            glds16b(ap2 + ((size_t)kb << 15) + (p << 13) + (t << 4), As + (p << 13) + (w << 10));
        // B: 2 rounds (one per tile); chunk byte offset within row = kb*128
        glds16b(gp8 + srcb[0] + ((size_t)kb << 7), Bs + (w << 10));
        glds16b(gp8 + srcb[1] + ((size_t)kb << 7), Bs + 8192 + (w << 10));
        __syncthreads();

        int8v af[4], bfr[4];
#pragma unroll
        for (int mf = 0; mf < 4; mf++) {
            int row = (wq << 6) + (mf << 4) + l15;
            int sw = row & 7;
            const u8* base = As + (row << 7);
            int4 lo = *(const int4*)(base + ((((kq << 1)    ) ^ sw) << 4));
            int4 hi = *(const int4*)(base + ((((kq << 1) | 1) ^ sw) << 4));
            int8v v; v[0]=lo.x; v[1]=lo.y; v[2]=lo.z; v[3]=lo.w; v[4]=hi.x; v[5]=hi.y; v[6]=hi.z; v[7]=hi.w;
            af[mf] = v;
        }
#pragma unroll
        for (int nf = 0; nf < 4; nf++) {
            int row = (nf << 4) + l15;
            int sw = row & 7;
            const u8* base = Bs + (ct << 13) + (row << 7);
            int4 lo = *(const int4*)(base + ((((kq << 1)    ) ^ sw) << 4));
            int4 hi = *(const int4*)(base + ((((kq << 1) | 1) ^ sw) << 4));
            int8v v; v[0]=lo.x; v[1]=lo.y; v[2]=lo.z; v[3]=lo.w; v[4]=hi.x; v[5]=hi.y; v[6]=hi.z; v[7]=hi.w;
            bfr[nf] = v;
        }
#pragma unroll
        for (int mf = 0; mf < 4; mf++)
#pragma unroll
            for (int nf = 0; nf < 4; nf++)
                acc[mf][nf] = __builtin_amdgcn_mfma_scale_f32_16x16x128_f8f6f4(
                    af[mf], bfr[nf], acc[mf][nf], 0, 0, 0, 0x7F7F7F7F, 0, 0x7F7F7F7F);
        __syncthreads();
    }

    // epilogue: undo 2^14 quant scale, +bias, relu (0-init), max over a
    const float SC = 6.103515625e-05f;   // 2^-14
    float vmax[4] = {0.f, 0.f, 0.f, 0.f};
#pragma unroll
    for (int mf = 0; mf < 4; mf++) {
#pragma unroll
        for (int r = 0; r < 4; r++) {
            float bias = cbf[wq * 64 + mf * 16 + kq * 4 + r];
#pragma unroll
            for (int nf = 0; nf < 4; nf++)
                vmax[nf] = fmaxf(vmax[nf], acc[mf][nf][r] * SC + bias);
        }
    }
#pragma unroll
    for (int nf = 0; nf < 4; nf++) {
        vmax[nf] = fmaxf(vmax[nf], __shfl_xor(vmax[nf], 16, 64));
        vmax[nf] = fmaxf(vmax[nf], __shfl_xor(vmax[nf], 32, 64));
    }
    if (l < 16) {
#pragma unroll
        for (int nf = 0; nf < 4; nf++) wred[ct * 256 + wq * 64 + nf * 16 + l] = vmax[nf];
    }
    __syncthreads();
    if (t < 128) {
        int ct2 = t >> 6, col = t & 63;
        float mm = fmaxf(fmaxf(wred[ct2 * 256 + col],       wred[ct2 * 256 + 64 + col]),
                         fmaxf(wred[ct2 * 256 + 128 + col], wred[ct2 * 256 + 192 + col]));
        mOut[c0 + t] = mm;     // packed: col == b*200+s
    }
}

// ================= FUSED tail: masked softmax -> z_s -> logits -> p_t -> r_s =================
// R10: dot loops unrolled x2 (two independent row loads in flight to cover L3/L2 latency).
__global__ __launch_bounds__(512) void k_tail(const int* __restrict__ x, const float* __restrict__ embf,
                                              const float* __restrict__ Tf, const float* __restrict__ Wwf,
                                              const float* __restrict__ Wbf, const float* __restrict__ mB,
                                              float* __restrict__ o_pt, float* __restrict__ o_zs,
                                              float* __restrict__ o_rs, float* __restrict__ o_ai,
                                              float* __restrict__ o_ptl) {
    __shared__ float aL[200];
    __shared__ int   tokL[200];
    __shared__ __align__(16) float zL[512];
    __shared__ float pL[256];
    __shared__ float lgt[256];
    __shared__ float red[512];
    __shared__ __align__(16) float part[4][512];
    int b = blockIdx.x, t = threadIdx.x;

    float v = 0.f;
    if (t < 200) {
        int tok = x[b * 200 + t];
        tokL[t] = tok;
        v = (tok == PADIDX) ? -1e13f : mB[b * 200 + t];
        red[t] = v;
    }
    __syncthreads();
    if (t < 64) {
        float m = -3.4e38f;
        for (int i = t; i < 200; i += 64) m = fmaxf(m, red[i]);
#pragma unroll
        for (int off = 32; off >= 1; off >>= 1) m = fmaxf(m, __shfl_xor(m, off, 64));
        if (t == 0) red[200] = m;
    }
    __syncthreads();
    float mx = red[200];
    float e = 0.f;
    if (t < 200) { e = expf(v - mx); red[t] = e; }
    __syncthreads();
    if (t < 64) {
        float s = 0.f;
        for (int i = t; i < 200; i += 64) s += red[i];
#pragma unroll
        for (int off = 32; off >= 1; off >>= 1) s += __shfl_xor(s, off, 64);
        if (t == 0) red[201] = s;
    }
    __syncthreads();
    float ainv = 1.0f / red[201];
    if (t < 200) {
        float a = e * ainv;
        aL[t] = a;
        o_ai[b * 200 + t] = a;
    }
    __syncthreads();

    // z_s: 4 lane-groups x 128 lanes, float4 rows, strided s; unroll 2 (50 iters even)
    {
        int g = t >> 7, l128 = t & 127;
        float4 zp = {0.f, 0.f, 0.f, 0.f};
#pragma unroll 5
        for (int i = 0; i < 50; i += 2) {
            int s0 = g + i * 4, s1 = s0 + 4;
            float a0 = aL[s0];
            float a1 = aL[s1];
            float4 r0 = ((const float4*)(embf + (size_t)tokL[s0] * E_))[l128];
            float4 r1 = ((const float4*)(embf + (size_t)tokL[s1] * E_))[l128];
            zp.x += a0 * r0.x + a1 * r1.x;
            zp.y += a0 * r0.y + a1 * r1.y;
            zp.z += a0 * r0.z + a1 * r1.z;
            zp.w += a0 * r0.w + a1 * r1.w;
        }
        *(float4*)(&part[g][l128 * 4]) = zp;
    }
    __syncthreads();
    {
        float z = part[0][t] + part[1][t] + part[2][t] + part[3][t];
        zL[t] = z;
        o_zs[(size_t)b * 512 + t] = z;
    }
    __syncthreads();

    // logits: (a = t&255, half h = t>>8), each half sums 256 e-dims
    {
        int a = t & 255, h = t >> 8;
        float acc = (h == 0) ? Wbf[a] : 0.f;
        const float4* wr = (const float4*)(Wwf + (size_t)a * E_ + h * 256);
        const float4* zz = (const float4*)(zL + h * 256);
#pragma unroll 4
        for (int i = 0; i < 64; i++) {
            float4 w4 = wr[i]; float4 z4 = zz[i];
            acc += w4.x*z4.x + w4.y*z4.y + w4.z*z4.z + w4.w*z4.w;
        }
        red[t] = acc;
    }
    __syncthreads();
    if (t < 256) {
        float lg = red[t] + red[t + 256];
        lgt[t] = lg;
        o_ptl[(size_t)b * 256 + t] = lg;
    }
    __syncthreads();
    if (t < 64) {
        float m = fmaxf(fmaxf(lgt[t], lgt[t + 64]), fmaxf(lgt[t + 128], lgt[t + 192]));
#pragma unroll
        for (int off = 32; off >= 1; off >>= 1) m = fmaxf(m, __shfl_xor(m, off, 64));
        if (t == 0) red[0] = m;
    }
    __syncthreads();
    float lmx = red[0];
    float pe = 0.f;
    if (t < 256) { pe = expf(lgt[t] - lmx); red[256 + t] = pe; }
    __syncthreads();
    if (t < 64) {
        float s = red[256 + t] + red[256 + t + 64] + red[256 + t + 128] + red[256 + t + 192];
#pragma unroll
        for (int off = 32; off >= 1; off >>= 1) s += __shfl_xor(s, off, 64);
        if (t == 0) red[1] = s;
    }
    __syncthreads();
    float pinv = 1.0f / red[1];
    if (t < 256) {
        float p = pe * pinv;
        pL[t] = p;
        o_pt[(size_t)b * 256 + t] = p;
    }
    __syncthreads();

    // r_s: 4 lane-groups x 128 lanes over a-quarters, float4 rows; unroll 2
    {
        int g = t >> 7, l128 = t & 127;
        float4 rp = {0.f, 0.f, 0.f, 0.f};
#pragma unroll 4
        for (int a = g * 64; a < g * 64 + 64; a += 2) {
            float p0 = pL[a];
            float p1 = pL[a + 1];
            float4 t0 = ((const float4*)(Tf + (size_t)a * E_))[l128];
            float4 t1 = ((const float4*)(Tf + (size_t)(a + 1) * E_))[l128];
            rp.x += p0 * t0.x + p1 * t1.x;
            rp.y += p0 * t0.y + p1 * t1.y;
            rp.z += p0 * t0.z + p1 * t1.z;
            rp.w += p0 * t0.w + p1 * t1.w;
        }
        *(float4*)(&part[g][l128 * 4]) = rp;
    }
    __syncthreads();
    o_rs[(size_t)b * 512 + t] = part[0][t] + part[1][t] + part[2][t] + part[3][t];
}

extern "C" void kernel_launch(void* const* d_in, const int* in_sizes, int n_in,
                              void* d_out, int out_size, void* d_ws, size_t ws_size,
                              hipStream_t stream) {
    if (ws_size < WS_NEEDED) return;
    const int*   x    = (const int*)d_in[0];
    const float* embf = (const float*)d_in[1];
    const float* Tf   = (const float*)d_in[2];
    const float* Wwf  = (const float*)d_in[3];
    const float* Wbf  = (const float*)d_in[4];
    const float* cwf  = (const float*)d_in[5];
    const float* cbf  = (const float*)d_in[6];

    char* ws = (char*)d_ws;
    u8*    gp8 = (u8*)(ws + GP8_OFF);
    u8*    ap2 = (u8*)(ws + AP2_OFF);
    u16*   T16 = (u16*)(ws + T16_OFF);
    float* rt  = (float*)(ws + RT_OFF);
    float* mB  = (float*)(ws + M_OFF);

    float* out   = (float*)d_out;
    float* o_pt  = out;                 // [B,A]
    float* o_zs  = out + 131072;        // [B,E]
    float* o_rs  = out + 393216;        // [B,E]
    float* o_ai  = out + 655360;        // [B,S]
    float* o_ptl = out + 757760;        // [B,A]

    k_halo   <<<512,   256, 0, stream>>>(gp8);
    k_cvtT   <<<256,   64,  0, stream>>>(Tf, T16, rt);
    k_prepack<<<256,   256, 0, stream>>>(cwf, ap2);
    k_ggemm  <<<800,   512, 0, stream>>>(x, embf, T16, rt, gp8);
    k_conv   <<<800,   512, 0, stream>>>(gp8, ap2, cbf, mB);
    k_tail   <<<512,   512, 0, stream>>>(x, embf, Tf, Wwf, Wbf, mB, o_pt, o_zs, o_rs, o_ai, o_ptl);
}

// Round 11
// 585.594 us; speedup vs baseline: 5.5532x; 1.0160x over previous
//
#include <hip/hip_runtime.h>

#define B_  512
#define S_  200
#define E_  512
#define A_  256
#define V_  50000
#define K_  51
#define PADIDX 1

typedef short short8_t __attribute__((ext_vector_type(8)));
typedef float float4_t __attribute__((ext_vector_type(4)));
typedef int   int8v    __attribute__((ext_vector_type(8)));
typedef unsigned short u16;
typedef unsigned int   u32;
typedef unsigned char  u8;

// ---------- f32 -> bf16 RNE (internal staging only) ----------
__device__ __forceinline__ u16 f2b(float f) {
    u32 x = __float_as_uint(f);
    return (u16)((x + 0x7fffu + ((x >> 16) & 1u)) >> 16);
}
// ---------- f32 -> fp8 e4m3 (OCP), via HW cvt ----------
__device__ __forceinline__ u8 f2fp8(float f) {
    int p = __builtin_amdgcn_cvt_pk_fp8_f32(f, 0.f, 0, false);
    return (u8)(p & 0xff);
}

// ---------- async global->LDS, 16B per lane ----------
__device__ __forceinline__ void glds16(const u16* g, short* l) {
    __builtin_amdgcn_global_load_lds(
        (const __attribute__((address_space(1))) unsigned int*)g,
        (__attribute__((address_space(3))) unsigned int*)l, 16, 0, 0);
}
__device__ __forceinline__ void glds16b(const u8* g, const u8* l) {
    __builtin_amdgcn_global_load_lds(
        (const __attribute__((address_space(1))) unsigned int*)g,
        (__attribute__((address_space(3))) unsigned int*)l, 16, 0, 0);
}

// ---------- workspace offsets (bytes); total guard 76,628,992 (proven) ----------
#define GP8_OFF   0ull
#define GP8_BYTES 33587200ull          // 131072 rows * 256 fp8 + 32KB slack
#define AP2_OFF   33587200ull          // packed+swizzled conv weights: 102*32768 fp8
#define RT_OFF    36929536ull          // 1/||T_a||   (256 f32)
#define M_OFF     37340160ull          // m[b,s]      (102400 f32)
#define T16_OFF   37749760ull          // T in bf16 (512KB)
#define P_OFF     41943040ull          // P[v][a] fp8 vocab-cosine table (12.8MB, ends 54.7MB)
#define WS_NEEDED 76628992ull

// ================= zero gp8 halo rows: b*256+[0,25) and b*256+[225,250) =================
__global__ __launch_bounds__(256) void k_halo(u8* __restrict__ gp8) {
    int b = blockIdx.x, t = threadIdx.x;
    size_t base = (size_t)b << 16;                 // 256 rows * 256 B
    float4 z = {0.f, 0.f, 0.f, 0.f};
#pragma unroll
    for (int rdx = 0; rdx < 4; rdx++) {
        int q = rdx * 256 + t;
        if (q < 400)      *(float4*)(gp8 + base + (size_t)q * 16) = z;                 // rows [0,25)
        else if (q < 800) *(float4*)(gp8 + base + 57600 + (size_t)(q - 400) * 16) = z; // rows [225,250)
    }
}

// ================= T (f32) -> bf16  +  1/||T_a||  (merged) =================
__global__ __launch_bounds__(64) void k_cvtT(const float* __restrict__ Tf, u16* __restrict__ T16,
                                             float* __restrict__ rt) {
    int a = blockIdx.x, l = threadIdx.x;
    const float* src = Tf + (size_t)a * E_ + l * 8;
    float4 d0 = *(const float4*)(src);
    float4 d1 = *(const float4*)(src + 4);
    ushort4 r0, r1;
    r0.x = f2b(d0.x); r0.y = f2b(d0.y); r0.z = f2b(d0.z); r0.w = f2b(d0.w);
    r1.x = f2b(d1.x); r1.y = f2b(d1.y); r1.z = f2b(d1.z); r1.w = f2b(d1.w);
    *(ushort4*)(T16 + (size_t)a * E_ + l * 8)     = r0;
    *(ushort4*)(T16 + (size_t)a * E_ + l * 8 + 4) = r1;
    float s = d0.x*d0.x + d0.y*d0.y + d0.z*d0.z + d0.w*d0.w
            + d1.x*d1.x + d1.y*d1.y + d1.z*d1.z + d1.w*d1.w;
#pragma unroll
    for (int off = 32; off >= 1; off >>= 1) s += __shfl_xor(s, off, 64);
    if (l == 0) rt[a] = (s > 0.f) ? 1.0f / sqrtf(s) : 0.0f;
}

// ========= pack conv_w (f32) -> ap2[kb][a][granule-swizzled 128B] fp8, scaled x512 =========
// COALESCED (proven R6): one block per output row r; linear float4 reads, LDS transpose,
// line-coalesced 16B stores. Bijection: kk = tap*256+i; kb=kk>>7; j=i&15; lg=(i>>4)&7;
// gslot = lg^(r&7); dst = ap2[kb*32768 + r*128 + gslot*16 + j] = fp8(cwf[r][i][tap]*512).
__global__ __launch_bounds__(256) void k_prepack(const float* __restrict__ cwf, u8* __restrict__ ap2) {
    __shared__ __align__(16) u8 L[13184];
    int r = blockIdx.x, t = threadIdx.x;
    int rs = r & 7;
    const float* src = cwf + (size_t)r * (A_ * K_);

    for (int q = 0; q < 13; q++) {
        int e4 = q * 256 + t;
        if (e4 < 3264) {
            float4 v = ((const float4*)src)[e4];
            float vals[4] = {v.x, v.y, v.z, v.w};
            int id0 = e4 * 4;
#pragma unroll
            for (int u = 0; u < 4; u++) {
                int id  = id0 + u;
                int i   = (int)(((unsigned long long)id * 84215046ull) >> 32);  // exact id/51
                int tap = id - i * 51;
                int kb  = tap * 2 + (i >> 7);
                int j   = i & 15;
                int lg  = (i >> 4) & 7;
                int off7 = ((lg ^ rs) << 4) | j;
                L[kb * 128 + (off7 ^ ((kb & 7) << 4))] = f2fp8(vals[u] * 512.0f);
            }
        }
    }
    __syncthreads();
#pragma unroll
    for (int q = 0; q < 4; q++) {
        int o16 = q * 256 + t;
        if (o16 < 816) {
            int byteo = o16 * 16;
            int kb = byteo >> 7;
            int p  = byteo & 127;
            int4 d = *(const int4*)(L + (byteo & ~127) + (p ^ ((kb & 7) << 4)));
            *(int4*)(ap2 + (size_t)kb * 32768 + (size_t)r * 128 + p) = d;
        }
    }
}

// ================= P[v][a] = fp8(cos(T_a, emb_v) x32) over the 50000-row VOCAB =================
// Replaces per-token ggemm: cosine depends only on vocab id (102400 tokens -> 50000 rows,
// gather -> LINEAR stream). R10 ggemm 8-wave structure verbatim; xbase = v*E (no x[] lookup);
// rx_v computed in-kernel (ssq during staging). 391 blocks x 128 rows (bounds-guarded).
__global__ __launch_bounds__(512, 4) void k_vgemm(const float* __restrict__ embf,
                                                  const u16* __restrict__ T16, const float* __restrict__ rt,
                                                  u8* __restrict__ P) {
    __shared__ __align__(16) short Xs[128 * 32];   // 8 KB
    __shared__ __align__(16) short Ts[256 * 32];   // 16 KB
    int t = threadIdx.x, l = t & 63, w = t >> 6;
    int wq = w & 3, ct = w >> 2;
    int c0 = blockIdx.x * 128;
    int crow  = t >> 2;                            // 128 rows, 4 threads/row
    int xslog = (t & 3) ^ ((crow >> 1) & 3);
    int vrow = c0 + crow; if (vrow > V_ - 1) vrow = V_ - 1;
    size_t xbase = (size_t)vrow * E_;

    float4_t acc[4][4];
#pragma unroll
    for (int mf = 0; mf < 4; mf++)
#pragma unroll
        for (int nf = 0; nf < 4; nf++) acc[mf][nf] = (float4_t){0.f, 0.f, 0.f, 0.f};

    float ssq = 0.f;                               // partial ||emb_v||^2 (8 elems/iter)

    for (int ec = 0; ec < 16; ec++) {
        int e0 = ec * 32;
        {
            const float* src = embf + xbase + e0 + xslog * 8;
            float4 f0 = *(const float4*)(src);
            float4 f1 = *(const float4*)(src + 4);
            ssq += f0.x*f0.x + f0.y*f0.y + f0.z*f0.z + f0.w*f0.w
                 + f1.x*f1.x + f1.y*f1.y + f1.z*f1.z + f1.w*f1.w;
            short8_t pk;
            pk[0] = (short)f2b(f0.x); pk[1] = (short)f2b(f0.y);
            pk[2] = (short)f2b(f0.z); pk[3] = (short)f2b(f0.w);
            pk[4] = (short)f2b(f1.x); pk[5] = (short)f2b(f1.y);
            pk[6] = (short)f2b(f1.z); pk[7] = (short)f2b(f1.w);
            *(short8_t*)(Xs + t * 8) = pk;
        }
#pragma unroll
        for (int p = 0; p < 2; p++) {              // 2 rounds x 512 threads cover 256 rows x 4 slots
            int idx  = p * 512 + t;
            int arow = idx >> 2;
            int slog = (idx & 3) ^ ((arow >> 1) & 3);
            glds16(T16 + (size_t)arow * E_ + e0 + slog * 8, Ts + (p * 512 + w * 64) * 8);
        }
        __syncthreads();
        int l15 = l & 15, q = l >> 4;
        short8_t af[4], bf[4];
#pragma unroll
        for (int mf = 0; mf < 4; mf++) {
            int row = (ct << 6) + (mf << 4) + l15;
            int kph = q ^ ((row >> 1) & 3);
            af[mf] = *(const short8_t*)(Xs + row * 32 + kph * 8);
        }
#pragma unroll
        for (int nf = 0; nf < 4; nf++) {
            int row = (wq << 6) + (nf << 4) + l15;
            int kph = q ^ ((row >> 1) & 3);
            bf[nf] = *(const short8_t*)(Ts + row * 32 + kph * 8);
        }
#pragma unroll
        for (int mf = 0; mf < 4; mf++)
#pragma unroll
            for (int nf = 0; nf < 4; nf++)
                acc[mf][nf] = __builtin_amdgcn_mfma_f32_16x16x32_bf16(af[mf], bf[nf], acc[mf][nf], 0, 0, 0);
        __syncthreads();
    }

    // reduce 4 ssq partials per row through dead Xs (512 floats = 2KB)
    float* rxs = (float*)Xs;
    rxs[t] = ssq;                        // t = crow*4 + (t&3)
    __syncthreads();

    int l15 = l & 15, q = l >> 4;
    float rta[4];
#pragma unroll
    for (int nf = 0; nf < 4; nf++) rta[nf] = rt[wq * 64 + nf * 16 + l15];
#pragma unroll
    for (int mf = 0; mf < 4; mf++) {
#pragma unroll
        for (int r = 0; r < 4; r++) {
            int cl = (ct << 6) + mf * 16 + q * 4 + r;
            int v = c0 + cl;
            float ss = rxs[cl * 4] + rxs[cl * 4 + 1] + rxs[cl * 4 + 2] + rxs[cl * 4 + 3];
            float rxc = ((ss > 0.f) ? 1.0f / sqrtf(ss) : 0.0f) * 32.0f;  // fp8 pre-scale
            if (v < V_) {
#pragma unroll
                for (int nf = 0; nf < 4; nf++) {
                    int a = wq * 64 + nf * 16 + l15;
                    P[(size_t)v * 256 + a] = f2fp8(acc[mf][nf][r] * rta[nf] * rxc);
                }
            }
        }
    }
}

// ================= gather: gp8[(b*256+25+s)*256 + .] = P[x[b,s]][.] (256B row copy) =================
__global__ __launch_bounds__(512) void k_gather(const int* __restrict__ x, const u8* __restrict__ P,
                                                u8* __restrict__ gp8) {
    int t = threadIdx.x;
    int c = blockIdx.x * 32 + (t >> 4);            // 32 token-cols per block
    int j = t & 15;
    int tok = x[c];
    int b = (int)(((unsigned long long)c * 167773ull) >> 25);   // exact c/200
    int s = c - b * 200;
    int4 d = *(const int4*)(P + (size_t)tok * 256 + j * 16);
    *(int4*)(gp8 + (size_t)(b * 256 + 25 + s) * 256 + j * 16) = d;
}

// ================= conv1d(A->A,k=51)+bias+relu+max_a -> m[col], packed N =================
// FROZEN at R8 (335us proven): 8-wave (4 row-quarters x 2 col-tiles), A staged once per
// chunk, stage-at-top 2-barrier loop, launch_bounds (512,4). R9's reorder regressed (342).
__global__ __launch_bounds__(512, 4) void k_conv(const u8* __restrict__ gp8, const u8* __restrict__ ap2,
                                                 const float* __restrict__ cbf, float* __restrict__ mOut) {
    __shared__ __align__(16) u8 smem[49152];     // As 32KB + Bs 16KB (2 tiles)
    u8* As = smem;
    u8* Bs = smem + 32768;
    float* wred = (float*)smem;                  // aliases As AFTER K-loop's final barrier (2KB)
    int t = threadIdx.x, l = t & 63, w = t >> 6;
    int wq = w & 3, ct = w >> 2;
    int c0 = blockIdx.x * 128;

    // B-staging bases: round p stages cols lc = p*64 + (t>>3) (tile p), granule t&7
    size_t srcb[2];
#pragma unroll
    for (int p = 0; p < 2; p++) {
        int lc = p * 64 + (t >> 3);
        int c = c0 + lc;
        int b = (int)(((unsigned long long)c * 167773ull) >> 25);   // exact c/200
        int s = c - b * 200;
        int gsw = (t & 7) ^ ((t >> 3) & 7);
        srcb[p] = (size_t)(b * 256 + s) * 256 + gsw * 16;
    }

    float4_t acc[4][4];
#pragma unroll
    for (int mf = 0; mf < 4; mf++)
#pragma unroll
        for (int nf = 0; nf < 4; nf++) acc[mf][nf] = (float4_t){0.f, 0.f, 0.f, 0.f};

    int l15 = l & 15, kq = l >> 4;

    for (int kb = 0; kb < 102; kb++) {
        // A: 4 linear rounds, 512 threads (ap2 pre-swizzled) — staged once for both tiles
#pragma unroll
        for (int p = 0; p < 4; p++)
            glds16b(ap2 + ((size_t)kb << 15) + (p << 13) + (t << 4), As + (p << 13) + (w << 10));
        // B: 2 rounds (one per tile); chunk byte offset within row = kb*128
        glds16b(gp8 + srcb[0] + ((size_t)kb << 7), Bs + (w << 10));
        glds16b(gp8 + srcb[1] + ((size_t)kb << 7), Bs + 8192 + (w << 10));
        __syncthreads();

        int8v af[4], bfr[4];
#pragma unroll
        for (int mf = 0; mf < 4; mf++) {
            int row = (wq << 6) + (mf << 4) + l15;
            int sw = row & 7;
            const u8* base = As + (row << 7);
            int4 lo = *(const int4*)(base + ((((kq << 1)    ) ^ sw) << 4));
            int4 hi = *(const int4*)(base + ((((kq << 1) | 1) ^ sw) << 4));
            int8v v; v[0]=lo.x; v[1]=lo.y; v[2]=lo.z; v[3]=lo.w; v[4]=hi.x; v[5]=hi.y; v[6]=hi.z; v[7]=hi.w;
            af[mf] = v;
        }
#pragma unroll
        for (int nf = 0; nf < 4; nf++) {
            int row = (nf << 4) + l15;
            int sw = row & 7;
            const u8* base = Bs + (ct << 13) + (row << 7);
            int4 lo = *(const int4*)(base + ((((kq << 1)    ) ^ sw) << 4));
            int4 hi = *(const int4*)(base + ((((kq << 1) | 1) ^ sw) << 4));
            int8v v; v[0]=lo.x; v[1]=lo.y; v[2]=lo.z; v[3]=lo.w; v[4]=hi.x; v[5]=hi.y; v[6]=hi.z; v[7]=hi.w;
            bfr[nf] = v;
        }
#pragma unroll
        for (int mf = 0; mf < 4; mf++)
#pragma unroll
            for (int nf = 0; nf < 4; nf++)
                acc[mf][nf] = __builtin_amdgcn_mfma_scale_f32_16x16x128_f8f6f4(
                    af[mf], bfr[nf], acc[mf][nf], 0, 0, 0, 0x7F7F7F7F, 0, 0x7F7F7F7F);
        __syncthreads();
    }

    // epilogue: undo 2^14 quant scale, +bias, relu (0-init), max over a
    const float SC = 6.103515625e-05f;   // 2^-14
    float vmax[4] = {0.f, 0.f, 0.f, 0.f};
#pragma unroll
    for (int mf = 0; mf < 4; mf++) {
#pragma unroll
        for (int r = 0; r < 4; r++) {
            float bias = cbf[wq * 64 + mf * 16 + kq * 4 + r];
#pragma unroll
            for (int nf = 0; nf < 4; nf++)
                vmax[nf] = fmaxf(vmax[nf], acc[mf][nf][r] * SC + bias);
        }
    }
#pragma unroll
    for (int nf = 0; nf < 4; nf++) {
        vmax[nf] = fmaxf(vmax[nf], __shfl_xor(vmax[nf], 16, 64));
        vmax[nf] = fmaxf(vmax[nf], __shfl_xor(vmax[nf], 32, 64));
    }
    if (l < 16) {
#pragma unroll
        for (int nf = 0; nf < 4; nf++) wred[ct * 256 + wq * 64 + nf * 16 + l] = vmax[nf];
    }
    __syncthreads();
    if (t < 128) {
        int ct2 = t >> 6, col = t & 63;
        float mm = fmaxf(fmaxf(wred[ct2 * 256 + col],       wred[ct2 * 256 + 64 + col]),
                         fmaxf(wred[ct2 * 256 + 128 + col], wred[ct2 * 256 + 192 + col]));
        mOut[c0 + t] = mm;     // packed: col == b*200+s
    }
}

// ================= FUSED tail: masked softmax -> z_s -> logits -> p_t -> r_s =================
// R10-proven: tree reductions, float4 row loads, x2 unrolled dot loops.
__global__ __launch_bounds__(512) void k_tail(const int* __restrict__ x, const float* __restrict__ embf,
                                              const float* __restrict__ Tf, const float* __restrict__ Wwf,
                                              const float* __restrict__ Wbf, const float* __restrict__ mB,
                                              float* __restrict__ o_pt, float* __restrict__ o_zs,
                                              float* __restrict__ o_rs, float* __restrict__ o_ai,
                                              float* __restrict__ o_ptl) {
    __shared__ float aL[200];
    __shared__ int   tokL[200];
    __shared__ __align__(16) float zL[512];
    __shared__ float pL[256];
    __shared__ float lgt[256];
    __shared__ float red[512];
    __shared__ __align__(16) float part[4][512];
    int b = blockIdx.x, t = threadIdx.x;

    float v = 0.f;
    if (t < 200) {
        int tok = x[b * 200 + t];
        tokL[t] = tok;
        v = (tok == PADIDX) ? -1e13f : mB[b * 200 + t];
        red[t] = v;
    }
    __syncthreads();
    if (t < 64) {
        float m = -3.4e38f;
        for (int i = t; i < 200; i += 64) m = fmaxf(m, red[i]);
#pragma unroll
        for (int off = 32; off >= 1; off >>= 1) m = fmaxf(m, __shfl_xor(m, off, 64));
        if (t == 0) red[200] = m;
    }
    __syncthreads();
    float mx = red[200];
    float e = 0.f;
    if (t < 200) { e = expf(v - mx); red[t] = e; }
    __syncthreads();
    if (t < 64) {
        float s = 0.f;
        for (int i = t; i < 200; i += 64) s += red[i];
#pragma unroll
        for (int off = 32; off >= 1; off >>= 1) s += __shfl_xor(s, off, 64);
        if (t == 0) red[201] = s;
    }
    __syncthreads();
    float ainv = 1.0f / red[201];
    if (t < 200) {
        float a = e * ainv;
        aL[t] = a;
        o_ai[b * 200 + t] = a;
    }
    __syncthreads();

    // z_s: 4 lane-groups x 128 lanes, float4 rows, strided s; unroll 2 (50 iters even)
    {
        int g = t >> 7, l128 = t & 127;
        float4 zp = {0.f, 0.f, 0.f, 0.f};
#pragma unroll 5
        for (int i = 0; i < 50; i += 2) {
            int s0 = g + i * 4, s1 = s0 + 4;
            float a0 = aL[s0];
            float a1 = aL[s1];
            float4 r0 = ((const float4*)(embf + (size_t)tokL[s0] * E_))[l128];
            float4 r1 = ((const float4*)(embf + (size_t)tokL[s1] * E_))[l128];
            zp.x += a0 * r0.x + a1 * r1.x;
            zp.y += a0 * r0.y + a1 * r1.y;
            zp.z += a0 * r0.z + a1 * r1.z;
            zp.w += a0 * r0.w + a1 * r1.w;
        }
        *(float4*)(&part[g][l128 * 4]) = zp;
    }
    __syncthreads();
    {
        float z = part[0][t] + part[1][t] + part[2][t] + part[3][t];
        zL[t] = z;
        o_zs[(size_t)b * 512 + t] = z;
    }
    __syncthreads();

    // logits: (a = t&255, half h = t>>8), each half sums 256 e-dims
    {
        int a = t & 255, h = t >> 8;
        float acc = (h == 0) ? Wbf[a] : 0.f;
        const float4* wr = (const float4*)(Wwf + (size_t)a * E_ + h * 256);
        const float4* zz = (const float4*)(zL + h * 256);
#pragma unroll 4
        for (int i = 0; i < 64; i++) {
            float4 w4 = wr[i]; float4 z4 = zz[i];
            acc += w4.x*z4.x + w4.y*z4.y + w4.z*z4.z + w4.w*z4.w;
        }
        red[t] = acc;
    }
    __syncthreads();
    if (t < 256) {
        float lg = red[t] + red[t + 256];
        lgt[t] = lg;
        o_ptl[(size_t)b * 256 + t] = lg;
    }
    __syncthreads();
    if (t < 64) {
        float m = fmaxf(fmaxf(lgt[t], lgt[t + 64]), fmaxf(lgt[t + 128], lgt[t + 192]));
#pragma unroll
        for (int off = 32; off >= 1; off >>= 1) m = fmaxf(m, __shfl_xor(m, off, 64));
        if (t == 0) red[0] = m;
    }
    __syncthreads();
    float lmx = red[0];
    float pe = 0.f;
    if (t < 256) { pe = expf(lgt[t] - lmx); red[256 + t] = pe; }
    __syncthreads();
    if (t < 64) {
        float s = red[256 + t] + red[256 + t + 64] + red[256 + t + 128] + red[256 + t + 192];
#pragma unroll
        for (int off = 32; off >= 1; off >>= 1) s += __shfl_xor(s, off, 64);
        if (t == 0) red[1] = s;
    }
    __syncthreads();
    float pinv = 1.0f / red[1];
    if (t < 256) {
        float p = pe * pinv;
        pL[t] = p;
        o_pt[(size_t)b * 256 + t] = p;
    }
    __syncthreads();

    // r_s: 4 lane-groups x 128 lanes over a-quarters, float4 rows; unroll 2
    {
        int g = t >> 7, l128 = t & 127;
        float4 rp = {0.f, 0.f, 0.f, 0.f};
#pragma unroll 4
        for (int a = g * 64; a < g * 64 + 64; a += 2) {
            float p0 = pL[a];
            float p1 = pL[a + 1];
            float4 t0 = ((const float4*)(Tf + (size_t)a * E_))[l128];
            float4 t1 = ((const float4*)(Tf + (size_t)(a + 1) * E_))[l128];
            rp.x += p0 * t0.x + p1 * t1.x;
            rp.y += p0 * t0.y + p1 * t1.y;
            rp.z += p0 * t0.z + p1 * t1.z;
            rp.w += p0 * t0.w + p1 * t1.w;
        }
        *(float4*)(&part[g][l128 * 4]) = rp;
    }
    __syncthreads();
    o_rs[(size_t)b * 512 + t] = part[0][t] + part[1][t] + part[2][t] + part[3][t];
}

extern "C" void kernel_launch(void* const* d_in, const int* in_sizes, int n_in,
                              void* d_out, int out_size, void* d_ws, size_t ws_size,
                              hipStream_t stream) {
    if (ws_size < WS_NEEDED) return;
    const int*   x    = (const int*)d_in[0];
    const float* embf = (const float*)d_in[1];
    const float* Tf   = (const float*)d_in[2];
    const float* Wwf  = (const float*)d_in[3];
    const float* Wbf  = (const float*)d_in[4];
    const float* cwf  = (const float*)d_in[5];
    const float* cbf  = (const float*)d_in[6];

    char* ws = (char*)d_ws;
    u8*    gp8 = (u8*)(ws + GP8_OFF);
    u8*    ap2 = (u8*)(ws + AP2_OFF);
    u16*   T16 = (u16*)(ws + T16_OFF);
    float* rt  = (float*)(ws + RT_OFF);
    float* mB  = (float*)(ws + M_OFF);
    u8*    P   = (u8*)(ws + P_OFF);

    float* out   = (float*)d_out;
    float* o_pt  = out;                 // [B,A]
    float* o_zs  = out + 131072;        // [B,E]
    float* o_rs  = out + 393216;        // [B,E]
    float* o_ai  = out + 655360;        // [B,S]
    float* o_ptl = out + 757760;        // [B,A]

    k_halo   <<<512,  256, 0, stream>>>(gp8);
    k_cvtT   <<<256,  64,  0, stream>>>(Tf, T16, rt);
    k_prepack<<<256,  256, 0, stream>>>(cwf, ap2);
    k_vgemm  <<<391,  512, 0, stream>>>(embf, T16, rt, P);
    k_gather <<<3200, 512, 0, stream>>>(x, P, gp8);
    k_conv   <<<800,  512, 0, stream>>>(gp8, ap2, cbf, mB);
    k_tail   <<<512,  512, 0, stream>>>(x, embf, Tf, Wwf, Wbf, mB, o_pt, o_zs, o_rs, o_ai, o_ptl);
}